// Round 18
// baseline (624.746 us; speedup 1.0000x reference)
//
#include <hip/hip_runtime.h>
#include <hip/hip_bf16.h>

// Problem constants (fixed-shape problem)
#define S_LEN  2048
#define NB     2
#define DIM    1024
#define KSEG   256
#define NLAYER 2
#define NHEAD  16
#define HDIM   64
#define FDIM   4096
#define NROW   (NB * S_LEN)   // 4096 token rows

typedef __bf16 bf16x8 __attribute__((ext_vector_type(8)));
typedef float  f32x4  __attribute__((ext_vector_type(4)));
typedef __hip_bfloat16 bf16_t;

struct __align__(8)  us4 { unsigned short v[4]; };
struct __align__(16) us8 { unsigned short v[8]; };

__device__ __forceinline__ unsigned short f2bf(float f) {
  __hip_bfloat16 t = __float2bfloat16(f);
  return __builtin_bit_cast(unsigned short, t);
}
__device__ __forceinline__ float bf2f(unsigned short x) {
  return __bfloat162float(__builtin_bit_cast(__hip_bfloat16, x));
}

// Async global->LDS, 16B per lane. LDS dest must be wave-uniform base; HW
// scatters lane i at base + i*16 (guide §5 / m104).
__device__ __forceinline__ void gload_lds16(const void* g, void* l) {
  __builtin_amdgcn_global_load_lds((__attribute__((address_space(1))) void*)g,
                                   (__attribute__((address_space(3))) void*)l,
                                   16, 0, 0);
}

__device__ __forceinline__ f32x4 mfma16(bf16x8 a, bf16x8 b, f32x4 c) {
  return __builtin_amdgcn_mfma_f32_16x16x32_bf16(a, b, c, 0, 0, 0);
}

// XOR-swizzle accessor for [rows][64] bf16 LDS tiles (128B row stride, T2/G4):
// byte = (r*128 + kElem*2) ^ ((r&7)<<4). Spreads the 16-rows-same-column
// fragment read across 8 distinct 16B slots (residual 2-way = free).
__device__ __forceinline__ bf16_t* swz(bf16_t* base, int r, int kElem) {
  int byte = ((r << 7) + (kElem << 1)) ^ ((r & 7) << 4);
  return (bf16_t*)((char*)base + byte);
}
__device__ __forceinline__ const bf16_t* swz(const bf16_t* base, int r, int kElem) {
  int byte = ((r << 7) + (kElem << 1)) ^ ((r & 7) << 4);
  return (const bf16_t*)((const char*)base + byte);
}

// ---------------------------------------------------------------------------
// ragged repeat-expand + residual add
// ---------------------------------------------------------------------------
__global__ __launch_bounds__(256) void expand_kernel(
    const float* __restrict__ xp, const int* __restrict__ bnd,
    const int* __restrict__ counts, const float* __restrict__ xres,
    const float* __restrict__ semb, float* __restrict__ x) {
  const int bt = blockIdx.x;
  const int b = bt >> 11, t = bt & (S_LEN - 1);
  const int cnt = counts[b];
  const int* bb = bnd + b * KSEG;
  int lo = 0, hi = KSEG;
  while (lo < hi) {
    int mid = (lo + hi) >> 1;
    int v = (mid < cnt) ? bb[mid] : S_LEN;
    if (v < t) lo = mid + 1; else hi = mid;
  }
  const float* src = (lo == 0) ? semb : (xp + ((size_t)b * KSEG + (lo - 1)) * DIM);
  const int tid = threadIdx.x;
  float4 a = ((const float4*)src)[tid];
  float4 r = ((const float4*)(xres + (size_t)bt * DIM))[tid];
  float4 w; w.x = a.x + r.x; w.y = a.y + r.y; w.z = a.z + r.z; w.w = a.w + r.w;
  ((float4*)(x + (size_t)bt * DIM))[tid] = w;
}

// ---------------------------------------------------------------------------
// RMSNorm: out = x * rsqrt(mean(x^2)+eps) * w ; one block per row of 1024
// ---------------------------------------------------------------------------
template <int F32OUT>
__global__ __launch_bounds__(256) void rmsnorm_kernel(
    const float* __restrict__ x, const float* __restrict__ wgt,
    bf16_t* __restrict__ ob, float* __restrict__ of) {
  const int row = blockIdx.x, tid = threadIdx.x;
  const float4 v = ((const float4*)(x + (size_t)row * DIM))[tid];
  float ss = v.x * v.x + v.y * v.y + v.z * v.z + v.w * v.w;
#pragma unroll
  for (int off = 1; off < 64; off <<= 1) ss += __shfl_xor(ss, off);
  __shared__ float red[4];
  if ((tid & 63) == 0) red[tid >> 6] = ss;
  __syncthreads();
  ss = red[0] + red[1] + red[2] + red[3];
  const float r = rsqrtf(ss * (1.0f / DIM) + 1e-5f);
  const float4 wv = ((const float4*)wgt)[tid];
  if (F32OUT) {
    float4 o4; o4.x = v.x * r * wv.x; o4.y = v.y * r * wv.y;
    o4.z = v.z * r * wv.z; o4.w = v.w * r * wv.w;
    ((float4*)(of + (size_t)row * DIM))[tid] = o4;
  } else {
    us4 p;
    p.v[0] = f2bf(v.x * r * wv.x); p.v[1] = f2bf(v.y * r * wv.y);
    p.v[2] = f2bf(v.z * r * wv.z); p.v[3] = f2bf(v.w * r * wv.w);
    ((us4*)(ob + (size_t)row * DIM))[tid] = p;
  }
}

// ---------------------------------------------------------------------------
// Transpose + cast f32[R][C] -> bf16[C][R]  (weights -> B^T layout)
// MODE 0: plain. MODE 1/2: gu-interleave — output row n remaps to
// (n>>4)*32 + (n&15) + (MODE==2 ? 16 : 0), so Wg rows and Wu rows alternate
// in 16-row groups. This puts silu-pair g/u for the SAME output column into
// the SAME lane in the fused FFN GEMM.
// ---------------------------------------------------------------------------
template <int MODE>
__global__ __launch_bounds__(256) void transpose_cast(
    const float* __restrict__ in, bf16_t* __restrict__ out, int R, int C) {
  __shared__ float tile[32][33];
  const int tx = threadIdx.x & 31, ty = threadIdx.x >> 5;  // 32 x 8
  const int cb = blockIdx.x * 32, rb = blockIdx.y * 32;
#pragma unroll
  for (int i = 0; i < 4; i++) {
    int r = ty + i * 8;
    tile[r][tx] = in[(size_t)(rb + r) * C + cb + tx];
  }
  __syncthreads();
#pragma unroll
  for (int i = 0; i < 4; i++) {
    int r = ty + i * 8;
    int n = cb + r;
    int dr = (MODE == 0) ? n : (((n >> 4) << 5) + (n & 15) + (MODE == 2 ? 16 : 0));
    out[(size_t)dr * R + rb + tx] = __float2bfloat16(tile[tx][r]);
  }
}

// ---------------------------------------------------------------------------
// 256x256 / BK=64 / 8-wave (2Mx4N) 8-phase GEMM, C = A[M,K] @ Bt[N,K]^T.
// m201 template: double-buffered 128KB LDS, T2 XOR-swizzle, counted vmcnt(6)
// at tile boundaries only, two raw barriers per phase, setprio around the
// MFMA cluster, rectangular per-XCD block swizzle.
// FUSE 0: C[r][c] = bf16(acc), ldc = N.
// FUSE 1: B̃ gu-interleaved; writes silu(g)*u (ldc 4096).
// FUSE 2: QKV with fused RoPE on q/k sections (bn<8); v sections (bn>=8)
//         write vT[(bh*64+dh)*2048 + t] DIRECTLY and skip the C store.
// ---------------------------------------------------------------------------
template <int FUSE>
__global__ __launch_bounds__(512, 2) void gemm_bt256(
    const bf16_t* __restrict__ A, const bf16_t* __restrict__ Bt,
    bf16_t* __restrict__ C, int ldc, int K, int lda, int nbn, int nbm,
    const float* __restrict__ cosb, const float* __restrict__ sinb,
    bf16_t* __restrict__ vTout) {
  __shared__ __align__(16) bf16_t As[2][256][64];
  __shared__ __align__(16) bf16_t Bs[2][256][64];
  const int bid = blockIdx.x;
  const int bmC = nbm >> 1, bnC = nbn >> 2;
  const int c8 = bid & 7, idx = bid >> 3;
  const int bm = (c8 & 1) * bmC + idx / bnC;
  const int bn = (c8 >> 1) * bnC + idx % bnC;
  const int tid = threadIdx.x;
  const int lane = tid & 63, w = tid >> 6;
  const int wm = w >> 2, wn = w & 3;               // 2M x 4N wave grid
  const int l15 = lane & 15, l16 = lane >> 4;
  const bf16_t* Ag = A + (size_t)bm * 256 * lda;
  const bf16_t* Bg = Bt + (size_t)bn * 256 * K;
  const int NT = K >> 6;

  f32x4 acc[8][4] = {};

  auto stage = [&](int j) {
    const int t = j >> 2, item = j & 3, buf = t & 1;
    bf16_t* dst;
    const bf16_t* src;
    int stride;
    if (item < 2) { dst = &Bs[buf][item * 128][0];
                    src = Bg + (size_t)item * 128 * K;  stride = K;   }
    else          { dst = &As[buf][(item - 2) * 128][0];
                    src = Ag + (size_t)(item - 2) * 128 * lda; stride = lda; }
    const int k0 = t << 6;
#pragma unroll
    for (int i = 0; i < 2; i++) {
      int c = i * 512 + tid;
      int row = c >> 3, q = c & 7;
      int colE = (q ^ (row & 7)) << 3;   // inverse swizzle on global source
      gload_lds16(src + (size_t)row * stride + k0 + colE, dst + c * 8);
    }
  };
  auto frag = [&](const bf16_t* tile, int row, int kk) -> bf16x8 {
    int byte = ((row << 7) + (kk << 6) + (l16 << 4)) ^ ((row & 7) << 4);
    return *(const bf16x8*)((const char*)tile + byte);
  };

  for (int j = 0; j < 7; j++) stage(j);
  asm volatile("s_waitcnt vmcnt(6)" ::: "memory");
  __builtin_amdgcn_s_barrier();

  for (int t = 0; t < NT; t++) {
    const int buf = t & 1;
    const bf16_t* At = &As[buf][0][0];
    const bf16_t* Bc = &Bs[buf][0][0];
    bf16x8 bfrg[4][2];
    const int jb = (t << 2) + 7;
#pragma unroll
    for (int p = 0; p < 4; p++) {
      bf16x8 afrg[2][2];
      if (p == 0) {
#pragma unroll
        for (int ni = 0; ni < 4; ni++)
#pragma unroll
          for (int kk = 0; kk < 2; kk++)
            bfrg[ni][kk] = frag(Bc, wn * 64 + ni * 16 + l15, kk);
      }
#pragma unroll
      for (int mi = 0; mi < 2; mi++)
#pragma unroll
        for (int kk = 0; kk < 2; kk++)
          afrg[mi][kk] = frag(At, wm * 128 + p * 32 + mi * 16 + l15, kk);
      if (jb + p < 4 * NT) stage(jb + p);
      __builtin_amdgcn_sched_barrier(0);
      __builtin_amdgcn_s_barrier();
      asm volatile("s_waitcnt lgkmcnt(0)" ::: "memory");
      __builtin_amdgcn_sched_barrier(0);
      __builtin_amdgcn_s_setprio(1);
#pragma unroll
      for (int mi = 0; mi < 2; mi++)
#pragma unroll
        for (int ni = 0; ni < 4; ni++)
#pragma unroll
          for (int kk = 0; kk < 2; kk++)
            acc[p * 2 + mi][ni] = mfma16(afrg[mi][kk], bfrg[ni][kk],
                                         acc[p * 2 + mi][ni]);
      __builtin_amdgcn_s_setprio(0);
      __builtin_amdgcn_sched_barrier(0);
      if (p == 3) {
        if (t < NT - 2) { asm volatile("s_waitcnt vmcnt(6)" ::: "memory"); }
        else            { asm volatile("s_waitcnt vmcnt(0)" ::: "memory"); }
      }
      __builtin_amdgcn_s_barrier();
    }
  }

  const int r0 = bm * 256 + wm * 128 + (l16 << 2);
  if (FUSE == 0) {
    const int c0 = bn * 256 + wn * 64 + l15;
#pragma unroll
    for (int mi = 0; mi < 8; mi++)
#pragma unroll
      for (int ni = 0; ni < 4; ni++)
#pragma unroll
        for (int r = 0; r < 4; r++)
          C[(size_t)(r0 + mi * 16 + r) * ldc + c0 + ni * 16] =
              __float2bfloat16(acc[mi][ni][r]);
  } else if (FUSE == 1) {
    const int c0 = bn * 128 + wn * 32 + l15;
#pragma unroll
    for (int mi = 0; mi < 8; mi++)
#pragma unroll
      for (int j = 0; j < 2; j++)
#pragma unroll
        for (int r = 0; r < 4; r++) {
          float g = acc[mi][2 * j][r], u = acc[mi][2 * j + 1][r];
          float a = g / (1.f + __expf(-g)) * u;
          C[(size_t)(r0 + mi * 16 + r) * ldc + c0 + j * 16] = __float2bfloat16(a);
        }
  } else {  // FUSE == 2
    const int c0 = bn * 256 + wn * 64 + l15;
    if (bn < 8) {   // q/k: cols < 2048 -> RoPE then store to qkv
#pragma unroll
      for (int mi = 0; mi < 8; mi++)
#pragma unroll
        for (int r = 0; r < 4; r++) {
          const int row = r0 + mi * 16 + r;
          const int tt = row & (S_LEN - 1);
#pragma unroll
          for (int ni = 0; ni < 2; ni++) {
            const int i = ni * 16 + l15;
            const float cz = cosb[tt * HDIM + i];
            const float sz = sinb[tt * HDIM + i];
            const float x1 = acc[mi][ni][r], x2 = acc[mi][ni + 2][r];
            C[(size_t)row * ldc + c0 + ni * 16] =
                __float2bfloat16(x1 * cz - x2 * sz);
            C[(size_t)row * ldc + c0 + (ni + 2) * 16] =
                __float2bfloat16(x2 * cz + x1 * sz);
          }
        }
    } else {        // v section: write vT[(bh*64+dh)*2048 + t] directly
      const int hh = (bn - 8) * 4 + wn;
      const int b = r0 >> 11, t0 = r0 & (S_LEN - 1);
#pragma unroll
      for (int mi = 0; mi < 8; mi++)
#pragma unroll
        for (int ni = 0; ni < 4; ni++) {
          us4 pk;
#pragma unroll
          for (int r = 0; r < 4; r++) pk.v[r] = f2bf(acc[mi][ni][r]);
          *(us4*)&vTout[((size_t)((b << 4) + hh) * 64 + ni * 16 + l15) * S_LEN
                        + t0 + mi * 16] = pk;
        }
    }
  }
}

// ---------------------------------------------------------------------------
// Small-N GEMM: 128M x 64N tile, BK=64, 256 threads / 4 waves (2M x 2N),
// ring-3 LDS (72KB -> 2 independent blocks/CU), depth-2 counted vmcnt
// (6 loads/thread/stage -> vmcnt(6)/vmcnt(0)). One raw s_barrier per iter.
// EPI 0: C bf16 store; EPI 1: Cf (f32) += acc  (fused residual add)
// ---------------------------------------------------------------------------
template <int EPI>
__global__ __launch_bounds__(256) void gemm_sn(
    const bf16_t* __restrict__ A, const bf16_t* __restrict__ Bt,
    bf16_t* __restrict__ Cb, float* __restrict__ Cf, int N, int K, int lda) {
  __shared__ __align__(16) bf16_t As[3][128][64];   // 16KB each
  __shared__ __align__(16) bf16_t Bs[3][64][64];    // 8KB each
  const int nbn = N >> 6;
  const int bid = blockIdx.x;
  const int sbid = (bid & 7) * (gridDim.x >> 3) + (bid >> 3);  // XCD-chunked
  const int bn = sbid % nbn, bm = sbid / nbn;
  const int tid = threadIdx.x, lane = tid & 63, w = tid >> 6;
  const int wm = w >> 1, wn = w & 1;              // 2M x 2N wave grid
  const int l15 = lane & 15, l16 = lane >> 4;
  const bf16_t* Ag = A + (size_t)bm * 128 * lda;
  const bf16_t* Bg = Bt + (size_t)bn * 64 * K;
  f32x4 acc[4][2] = {};
  const int NT = K >> 6;

  // stage: A 16KB (1024 chunks, 4/thread) + B 8KB (512 chunks, 2/thread)
  auto stage = [&](int buf, int t) {
    const int k0 = t << 6;
#pragma unroll
    for (int i = 0; i < 4; i++) {
      int c = i * 256 + tid;
      int row = c >> 3, q = c & 7;
      int colE = (q ^ (row & 7)) << 3;            // inverse swizzle on source
      gload_lds16(Ag + (size_t)row * lda + k0 + colE, &As[buf][0][0] + c * 8);
    }
#pragma unroll
    for (int i = 0; i < 2; i++) {
      int c = i * 256 + tid;
      int row = c >> 3, q = c & 7;
      int colE = (q ^ (row & 7)) << 3;
      gload_lds16(Bg + (size_t)row * K + k0 + colE, &Bs[buf][0][0] + c * 8);
    }
  };
  // swizzled fragment read: kk = K-half (0/1), 16B slot = kk*4 + l16
  auto frag = [&](const bf16_t* base, int row, int kk) -> bf16x8 {
    int byte = ((row << 7) + (kk << 6) + (l16 << 4)) ^ ((row & 7) << 4);
    return *(const bf16x8*)((const char*)base + byte);
  };

  stage(0, 0);
  if (NT > 1) stage(1, 1);
  int bi = 0;
  for (int t = 0; t < NT; t++) {
    if (t + 1 < NT) { asm volatile("s_waitcnt vmcnt(6)" ::: "memory"); }
    else            { asm volatile("s_waitcnt vmcnt(0)" ::: "memory"); }
    __builtin_amdgcn_s_barrier();
    __builtin_amdgcn_sched_barrier(0);
    if (t + 2 < NT) {
      int nb = bi + 2; if (nb >= 3) nb -= 3;
      stage(nb, t + 2);
    }
    __builtin_amdgcn_sched_barrier(0);
    const bf16_t* Ab = &As[bi][0][0];
    const bf16_t* Bb = &Bs[bi][0][0];
    bf16x8 af[4][2], bfr[2][2];
#pragma unroll
    for (int mi = 0; mi < 4; mi++)
#pragma unroll
      for (int kk = 0; kk < 2; kk++)
        af[mi][kk] = frag(Ab, wm * 64 + mi * 16 + l15, kk);
#pragma unroll
    for (int ni = 0; ni < 2; ni++)
#pragma unroll
      for (int kk = 0; kk < 2; kk++)
        bfr[ni][kk] = frag(Bb, wn * 32 + ni * 16 + l15, kk);
    __builtin_amdgcn_s_setprio(1);
#pragma unroll
    for (int mi = 0; mi < 4; mi++)
#pragma unroll
      for (int ni = 0; ni < 2; ni++)
#pragma unroll
        for (int kk = 0; kk < 2; kk++)
          acc[mi][ni] = mfma16(af[mi][kk], bfr[ni][kk], acc[mi][ni]);
    __builtin_amdgcn_s_setprio(0);
    __builtin_amdgcn_sched_barrier(0);   // keep reads+MFMA before next barrier
    bi++; if (bi >= 3) bi -= 3;
  }

  const int r0 = bm * 128 + wm * 64 + (l16 << 2);
  const int c0 = bn * 64 + wn * 32 + l15;
#pragma unroll
  for (int mi = 0; mi < 4; mi++)
#pragma unroll
    for (int ni = 0; ni < 2; ni++)
#pragma unroll
      for (int r = 0; r < 4; r++) {
        size_t off = (size_t)(r0 + mi * 16 + r) * N + c0 + ni * 16;
        if (EPI == 0) Cb[off] = __float2bfloat16(acc[mi][ni][r]);
        else          Cf[off] += acc[mi][ni][r];
      }
}

// ---------------------------------------------------------------------------
// Flash attention v8 (r15 ring + T14 V-to-reg): block = (bh, pair) covering
// 64-row q-tiles {p, 31-p} (grid 512 = 2 blocks/CU). K stays LDS-staged
// (ring-3, depth-2 counted vmcnt — the staging IS the prefetch, r16 lesson);
// V is loaded DIRECT-TO-REGISTER at step top (issued BEFORE the K-stage so
// the compiler's pre-use wait is a counted vmcnt leaving the stage in
// flight); V latency hides under QK^T + softmax. Deletes V's LDS staging +
// 8 ds_read_b128/wave-step (the LDS pipe was the measured critical path).
// S^T-swapped QK; 2-shfl softmax; packed b64 P-writes; exp2, Q pre-scaled.
// ---------------------------------------------------------------------------
__global__ __launch_bounds__(256) void attn_kernel(
    const bf16_t* __restrict__ qkv, const bf16_t* __restrict__ vT,
    bf16_t* __restrict__ o) {
  __shared__ __align__(16) bf16_t Ks[3][64][64];
  __shared__ __align__(16) bf16_t Ps[64][64];
  const int bid = blockIdx.x;
  const int pair = (bid >> 3) & 15;
  const int bh = (bid & 7) + ((bid >> 7) << 3);
  const int b = bh >> 4, h = bh & 15;
  const int tid = threadIdx.x, lane = tid & 63, w = tid >> 6;
  const int l15 = lane & 15;
  const int kq = (lane >> 4) << 3;
  const int rq = (lane >> 4) << 2;
  const bf16_t* kbase = qkv + (size_t)b * S_LEN * 3072 + 1024 + h * HDIM;
  const bf16_t* vbase = vT + ((size_t)bh * 64) * S_LEN;

  bf16x8 ones;
#pragma unroll
  for (int e = 0; e < 8; e++) ones[e] = (__bf16)1.0f;

#define STAGEK(buf, kt) do {                                                   \
    const bf16_t* kg_ = kbase + (size_t)(kt) * 64 * 3072;                      \
    _Pragma("unroll")                                                          \
    for (int i_ = 0; i_ < 2; i_++) {                                           \
      int cb_ = i_ * 256 + w * 64;                                             \
      int c_ = cb_ + lane;                                                     \
      int row_ = c_ >> 3;                                                      \
      int colE_ = ((c_ & 7) ^ (row_ & 7)) << 3;                                \
      gload_lds16(kg_ + (size_t)row_ * 3072 + colE_,                           \
                  &Ks[buf][0][0] + (size_t)cb_ * 8);                           \
    }                                                                          \
  } while (0)

  for (int ph = 0; ph < 2; ph++) {
    const int qb = (ph == 0) ? pair : (31 - pair);
    const int nk = qb + 1;
    const int qrow = qb * 64 + w * 16 + l15;
    const bf16_t* qg = qkv + ((size_t)(b * S_LEN + qrow)) * 3072 + h * HDIM;
    bf16x8 aq0 = *(const bf16x8*)(qg + kq);
    bf16x8 aq1 = *(const bf16x8*)(qg + 32 + kq);
    const float qsc = 0.125f * 1.44269504088896340736f;
#pragma unroll
    for (int e = 0; e < 8; e++) {
      aq0[e] = (__bf16)((float)aq0[e] * qsc);
      aq1[e] = (__bf16)((float)aq1[e] * qsc);
    }
    f32x4 oacc[4] = {};
    f32x4 lacc = {0.f, 0.f, 0.f, 0.f};
    float m_s = -1e30f;                 // per-thread q = w*16 + l15
    const int myq = qb * 64 + w * 16 + l15;

    // protect ring buffers from the previous phase's readers (cross-wave)
    __builtin_amdgcn_s_barrier();
    STAGEK(0, 0);
    if (nk > 1) STAGEK(1, 1);
    int bi = 0;
    for (int kt = 0; kt < nk; kt++) {
      if (kt + 1 < nk) { asm volatile("s_waitcnt vmcnt(2)" ::: "memory"); }
      else             { asm volatile("s_waitcnt vmcnt(0)" ::: "memory"); }
      __builtin_amdgcn_s_barrier();
      __builtin_amdgcn_sched_barrier(0);
      // V direct-to-reg, issued FIRST (oldest) so the compiler's pre-use
      // wait is a counted vmcnt leaving the younger K-stage in flight.
      bf16x8 vreg[2][4];
#pragma unroll
      for (int kk2 = 0; kk2 < 2; kk2++)
#pragma unroll
        for (int ni = 0; ni < 4; ni++)
          vreg[kk2][ni] = *(const bf16x8*)(vbase
                            + (size_t)(ni * 16 + l15) * S_LEN
                            + kt * 64 + kk2 * 32 + kq);
      if (kt + 2 < nk) {
        int nb = bi + 2; if (nb >= 3) nb -= 3;
        STAGEK(nb, kt + 2);
      }
      __builtin_amdgcn_sched_barrier(0);
      const bf16_t* Kc = &Ks[bi][0][0];
      // S^T = K Q^T (swapped operands): col = q (l15), row = kv (rq + reg)
      f32x4 st[4];
      __builtin_amdgcn_s_setprio(1);
#pragma unroll
      for (int f = 0; f < 4; f++) {
        bf16x8 bk0 = *(const bf16x8*)swz(Kc, f * 16 + l15, kq);
        bf16x8 bk1 = *(const bf16x8*)swz(Kc, f * 16 + l15, 32 + kq);
        f32x4 t = {};
        t = mfma16(bk0, aq0, t);
        t = mfma16(bk1, aq1, t);
        st[f] = t;
      }
      __builtin_amdgcn_s_setprio(0);
      if (kt == qb) {   // causal: kv_global > q_global -> -inf
#pragma unroll
        for (int f = 0; f < 4; f++) {
          int kvb = kt * 64 + f * 16 + rq;
#pragma unroll
          for (int r = 0; r < 4; r++)
            if (kvb + r > myq) st[f][r] = -1e30f;
        }
      }
      // per-thread row max over 16 kv + 2 shfl across rq-groups
      float mx = -1e30f;
#pragma unroll
      for (int f = 0; f < 4; f++)
#pragma unroll
        for (int r = 0; r < 4; r++) mx = fmaxf(mx, st[f][r]);
      mx = fmaxf(mx, __shfl_xor(mx, 16));
      mx = fmaxf(mx, __shfl_xor(mx, 32));
      const float mn = fmaxf(m_s, mx);
      const float alpha = exp2f(m_s - mn);
      m_s = mn;
#pragma unroll
      for (int f = 0; f < 4; f++)
#pragma unroll
        for (int r = 0; r < 4; r++) st[f][r] = exp2f(st[f][r] - mn);
      // alpha for PV row layout (q = w*16 + rq + r): source lane l15 = rq + r
      float alpr[4];
#pragma unroll
      for (int r = 0; r < 4; r++) alpr[r] = __shfl(alpha, rq + r);
#pragma unroll
      for (int ni = 0; ni < 4; ni++)
#pragma unroll
        for (int r = 0; r < 4; r++) oacc[ni][r] *= alpr[r];
#pragma unroll
      for (int r = 0; r < 4; r++) lacc[r] *= alpr[r];
      // P -> LDS: thread holds 4 consecutive kv at fixed q -> 4 b64 writes
#pragma unroll
      for (int f = 0; f < 4; f++) {
        us4 pk;
#pragma unroll
        for (int r = 0; r < 4; r++) pk.v[r] = f2bf(st[f][r]);
        *(us4*)swz(&Ps[0][0], w * 16 + l15, f * 16 + rq) = pk;
      }
      __builtin_amdgcn_s_setprio(1);
#pragma unroll
      for (int kk2 = 0; kk2 < 2; kk2++) {
        bf16x8 ap = *(const bf16x8*)swz(&Ps[0][0], w * 16 + l15, kk2 * 32 + kq);
        lacc = mfma16(ap, ones, lacc);
#pragma unroll
        for (int ni = 0; ni < 4; ni++)
          oacc[ni] = mfma16(ap, vreg[kk2][ni], oacc[ni]);
      }
      __builtin_amdgcn_s_setprio(0);
      __builtin_amdgcn_sched_barrier(0);  // keep reads+MFMA before next barrier
      bi++; if (bi >= 3) bi -= 3;
    }
    bf16_t* ob = o + ((size_t)(b * S_LEN + qb * 64 + w * 16 + rq)) * DIM + h * HDIM + l15;
#pragma unroll
    for (int r = 0; r < 4; r++) {
      float inv = 1.0f / lacc[r];
#pragma unroll
      for (int ni = 0; ni < 4; ni++)
        ob[(size_t)r * DIM + ni * 16] = __float2bfloat16(oacc[ni][r] * inv);
    }
  }
#undef STAGEK
}

// ---------------------------------------------------------------------------
extern "C" void kernel_launch(void* const* d_in, const int* in_sizes, int n_in,
                              void* d_out, int out_size, void* d_ws, size_t ws_size,
                              hipStream_t stream) {
  (void)in_sizes; (void)n_in; (void)out_size; (void)ws_size;
  const float* x_processed = (const float*)d_in[0];
  const int*   boundaries  = (const int*)d_in[1];
  const int*   counts      = (const int*)d_in[2];
  const float* x_residual  = (const float*)d_in[3];
  const float* cos_t       = (const float*)d_in[4];
  const float* sin_t       = (const float*)d_in[5];
  // d_in[6] = seq_len (constant 2048, compiled in)
  const float* start_emb   = (const float*)d_in[7];
  const float* Wq  = (const float*)d_in[8];
  const float* Wk  = (const float*)d_in[9];
  const float* Wv  = (const float*)d_in[10];
  const float* Wo  = (const float*)d_in[11];
  const float* Wg  = (const float*)d_in[12];
  const float* Wu  = (const float*)d_in[13];
  const float* Wd  = (const float*)d_in[14];
  const float* ln1 = (const float*)d_in[15];
  const float* ln2 = (const float*)d_in[16];
  const float* fnm = (const float*)d_in[17];

  // Workspace layout (120 MB, lifetime-overlapped):
  char* ws = (char*)d_ws;
  const size_t MB = (size_t)1 << 20;
  float*  x      = (float*)(ws);            // 16MB  residual stream f32
  bf16_t* h      = (bf16_t*)(ws + 16 * MB); // 8MB   rms output bf16
  bf16_t* Wqkv_t = (bf16_t*)(ws + 24 * MB); // 6MB   [3072][1024]
  bf16_t* Wo_t   = (bf16_t*)(ws + 30 * MB); // 2MB   [1024][1024]
  bf16_t* Wgu_t  = (bf16_t*)(ws + 32 * MB); // 16MB  B̃[8192][1024] interleaved
  bf16_t* Wd_t   = (bf16_t*)(ws + 48 * MB); // 8MB   [1024][4096]
  char*   Rg     = ws + 56 * MB;            // 64MB shared region
  bf16_t* qkv  = (bf16_t*)(Rg);             // 24MB [4096][3072]
  bf16_t* vT   = (bf16_t*)(Rg + 24 * MB);   // 8MB  [32][64][2048]
  bf16_t* obuf = (bf16_t*)(Rg + 32 * MB);   // 8MB  [4096][1024]
  bf16_t* act  = (bf16_t*)(Rg);             // 32MB [4096][4096] (after attn)

  expand_kernel<<<NROW, 256, 0, stream>>>(x_processed, boundaries, counts,
                                          x_residual, start_emb, x);

  const size_t dd = (size_t)DIM * DIM, df = (size_t)DIM * FDIM;
  for (int l = 0; l < NLAYER; l++) {
    transpose_cast<0><<<dim3(DIM / 32, DIM / 32), 256, 0, stream>>>(Wq + l * dd, Wqkv_t, DIM, DIM);
    transpose_cast<0><<<dim3(DIM / 32, DIM / 32), 256, 0, stream>>>(Wk + l * dd, Wqkv_t + dd, DIM, DIM);
    transpose_cast<0><<<dim3(DIM / 32, DIM / 32), 256, 0, stream>>>(Wv + l * dd, Wqkv_t + 2 * dd, DIM, DIM);
    transpose_cast<0><<<dim3(DIM / 32, DIM / 32), 256, 0, stream>>>(Wo + l * dd, Wo_t, DIM, DIM);
    transpose_cast<1><<<dim3(FDIM / 32, DIM / 32), 256, 0, stream>>>(Wg + l * df, Wgu_t, DIM, FDIM);
    transpose_cast<2><<<dim3(FDIM / 32, DIM / 32), 256, 0, stream>>>(Wu + l * df, Wgu_t, DIM, FDIM);
    transpose_cast<0><<<dim3(DIM / 32, FDIM / 32), 256, 0, stream>>>(Wd + l * df, Wd_t, FDIM, DIM);

    rmsnorm_kernel<0><<<NROW, 256, 0, stream>>>(x, ln1 + l * DIM, h, nullptr);
    gemm_bt256<2><<<(3072 / 256) * (NROW / 256), 512, 0, stream>>>(
        h, Wqkv_t, qkv, 3072, DIM, DIM, 3072 / 256, NROW / 256, cos_t, sin_t, vT);
    attn_kernel<<<512, 256, 0, stream>>>(qkv, vT, obuf);
    gemm_sn<1><<<(DIM / 64) * (NROW / 128), 256, 0, stream>>>(
        obuf, Wo_t, nullptr, x, DIM, DIM, DIM);

    rmsnorm_kernel<0><<<NROW, 256, 0, stream>>>(x, ln2 + l * DIM, h, nullptr);
    gemm_bt256<1><<<(2 * FDIM / 256) * (NROW / 256), 512, 0, stream>>>(
        h, Wgu_t, act, FDIM, DIM, DIM, 2 * FDIM / 256, NROW / 256,
        nullptr, nullptr, nullptr);
    gemm_sn<1><<<(DIM / 64) * (NROW / 128), 256, 0, stream>>>(
        act, Wd_t, nullptr, x, DIM, FDIM, FDIM);
  }
  rmsnorm_kernel<1><<<NROW, 256, 0, stream>>>(x, fnm, nullptr, (float*)d_out);
}

// Round 19
// 586.523 us; speedup vs baseline: 1.0652x; 1.0652x over previous
//
#include <hip/hip_runtime.h>
#include <hip/hip_bf16.h>

// Problem constants (fixed-shape problem)
#define S_LEN  2048
#define NB     2
#define DIM    1024
#define KSEG   256
#define NLAYER 2
#define NHEAD  16
#define HDIM   64
#define FDIM   4096
#define NROW   (NB * S_LEN)   // 4096 token rows

typedef __bf16 bf16x8 __attribute__((ext_vector_type(8)));
typedef float  f32x4  __attribute__((ext_vector_type(4)));
typedef __hip_bfloat16 bf16_t;

struct __align__(8)  us4 { unsigned short v[4]; };
struct __align__(16) us8 { unsigned short v[8]; };

__device__ __forceinline__ unsigned short f2bf(float f) {
  __hip_bfloat16 t = __float2bfloat16(f);
  return __builtin_bit_cast(unsigned short, t);
}
__device__ __forceinline__ float bf2f(unsigned short x) {
  return __bfloat162float(__builtin_bit_cast(__hip_bfloat16, x));
}

// Async global->LDS, 16B per lane. LDS dest must be wave-uniform base; HW
// scatters lane i at base + i*16 (guide §5 / m104).
__device__ __forceinline__ void gload_lds16(const void* g, void* l) {
  __builtin_amdgcn_global_load_lds((__attribute__((address_space(1))) void*)g,
                                   (__attribute__((address_space(3))) void*)l,
                                   16, 0, 0);
}

__device__ __forceinline__ f32x4 mfma16(bf16x8 a, bf16x8 b, f32x4 c) {
  return __builtin_amdgcn_mfma_f32_16x16x32_bf16(a, b, c, 0, 0, 0);
}

// XOR-swizzle accessor for [rows][64] bf16 LDS tiles (128B row stride, T2/G4):
// byte = (r*128 + kElem*2) ^ ((r&7)<<4). Spreads the 16-rows-same-column
// fragment read across 8 distinct 16B slots (residual 2-way = free).
__device__ __forceinline__ bf16_t* swz(bf16_t* base, int r, int kElem) {
  int byte = ((r << 7) + (kElem << 1)) ^ ((r & 7) << 4);
  return (bf16_t*)((char*)base + byte);
}
__device__ __forceinline__ const bf16_t* swz(const bf16_t* base, int r, int kElem) {
  int byte = ((r << 7) + (kElem << 1)) ^ ((r & 7) << 4);
  return (const bf16_t*)((const char*)base + byte);
}

// ---------------------------------------------------------------------------
// ragged repeat-expand + residual add
// ---------------------------------------------------------------------------
__global__ __launch_bounds__(256) void expand_kernel(
    const float* __restrict__ xp, const int* __restrict__ bnd,
    const int* __restrict__ counts, const float* __restrict__ xres,
    const float* __restrict__ semb, float* __restrict__ x) {
  const int bt = blockIdx.x;
  const int b = bt >> 11, t = bt & (S_LEN - 1);
  const int cnt = counts[b];
  const int* bb = bnd + b * KSEG;
  int lo = 0, hi = KSEG;
  while (lo < hi) {
    int mid = (lo + hi) >> 1;
    int v = (mid < cnt) ? bb[mid] : S_LEN;
    if (v < t) lo = mid + 1; else hi = mid;
  }
  const float* src = (lo == 0) ? semb : (xp + ((size_t)b * KSEG + (lo - 1)) * DIM);
  const int tid = threadIdx.x;
  float4 a = ((const float4*)src)[tid];
  float4 r = ((const float4*)(xres + (size_t)bt * DIM))[tid];
  float4 w; w.x = a.x + r.x; w.y = a.y + r.y; w.z = a.z + r.z; w.w = a.w + r.w;
  ((float4*)(x + (size_t)bt * DIM))[tid] = w;
}

// ---------------------------------------------------------------------------
// RMSNorm: out = x * rsqrt(mean(x^2)+eps) * w ; one block per row of 1024
// ---------------------------------------------------------------------------
template <int F32OUT>
__global__ __launch_bounds__(256) void rmsnorm_kernel(
    const float* __restrict__ x, const float* __restrict__ wgt,
    bf16_t* __restrict__ ob, float* __restrict__ of) {
  const int row = blockIdx.x, tid = threadIdx.x;
  const float4 v = ((const float4*)(x + (size_t)row * DIM))[tid];
  float ss = v.x * v.x + v.y * v.y + v.z * v.z + v.w * v.w;
#pragma unroll
  for (int off = 1; off < 64; off <<= 1) ss += __shfl_xor(ss, off);
  __shared__ float red[4];
  if ((tid & 63) == 0) red[tid >> 6] = ss;
  __syncthreads();
  ss = red[0] + red[1] + red[2] + red[3];
  const float r = rsqrtf(ss * (1.0f / DIM) + 1e-5f);
  const float4 wv = ((const float4*)wgt)[tid];
  if (F32OUT) {
    float4 o4; o4.x = v.x * r * wv.x; o4.y = v.y * r * wv.y;
    o4.z = v.z * r * wv.z; o4.w = v.w * r * wv.w;
    ((float4*)(of + (size_t)row * DIM))[tid] = o4;
  } else {
    us4 p;
    p.v[0] = f2bf(v.x * r * wv.x); p.v[1] = f2bf(v.y * r * wv.y);
    p.v[2] = f2bf(v.z * r * wv.z); p.v[3] = f2bf(v.w * r * wv.w);
    ((us4*)(ob + (size_t)row * DIM))[tid] = p;
  }
}

// ---------------------------------------------------------------------------
// Transpose + cast f32[R][C] -> bf16[C][R]  (weights -> B^T layout)
// MODE 0: plain. MODE 1/2: gu-interleave — output row n remaps to
// (n>>4)*32 + (n&15) + (MODE==2 ? 16 : 0), so Wg rows and Wu rows alternate
// in 16-row groups. This puts silu-pair g/u for the SAME output column into
// the SAME lane in the fused FFN GEMM.
// ---------------------------------------------------------------------------
template <int MODE>
__global__ __launch_bounds__(256) void transpose_cast(
    const float* __restrict__ in, bf16_t* __restrict__ out, int R, int C) {
  __shared__ float tile[32][33];
  const int tx = threadIdx.x & 31, ty = threadIdx.x >> 5;  // 32 x 8
  const int cb = blockIdx.x * 32, rb = blockIdx.y * 32;
#pragma unroll
  for (int i = 0; i < 4; i++) {
    int r = ty + i * 8;
    tile[r][tx] = in[(size_t)(rb + r) * C + cb + tx];
  }
  __syncthreads();
#pragma unroll
  for (int i = 0; i < 4; i++) {
    int r = ty + i * 8;
    int n = cb + r;
    int dr = (MODE == 0) ? n : (((n >> 4) << 5) + (n & 15) + (MODE == 2 ? 16 : 0));
    out[(size_t)dr * R + rb + tx] = __float2bfloat16(tile[tx][r]);
  }
}

// ---------------------------------------------------------------------------
// 256x256 / BK=64 / 8-wave (2Mx4N) 8-phase GEMM, C = A[M,K] @ Bt[N,K]^T.
// m201 template: double-buffered 128KB LDS, T2 XOR-swizzle, counted vmcnt(6)
// at tile boundaries only, two raw barriers per phase, setprio around the
// MFMA cluster, rectangular per-XCD block swizzle.
// FUSE 0: C[r][c] = bf16(acc), ldc = N.
// FUSE 1: B̃ gu-interleaved; writes silu(g)*u (ldc 4096).
// FUSE 2: QKV with fused RoPE on q/k sections (bn<8); v sections (bn>=8)
//         write vT[(bh*64+dh)*2048 + t] DIRECTLY and skip the C store.
// ---------------------------------------------------------------------------
template <int FUSE>
__global__ __launch_bounds__(512, 2) void gemm_bt256(
    const bf16_t* __restrict__ A, const bf16_t* __restrict__ Bt,
    bf16_t* __restrict__ C, int ldc, int K, int lda, int nbn, int nbm,
    const float* __restrict__ cosb, const float* __restrict__ sinb,
    bf16_t* __restrict__ vTout) {
  __shared__ __align__(16) bf16_t As[2][256][64];
  __shared__ __align__(16) bf16_t Bs[2][256][64];
  const int bid = blockIdx.x;
  const int bmC = nbm >> 1, bnC = nbn >> 2;
  const int c8 = bid & 7, idx = bid >> 3;
  const int bm = (c8 & 1) * bmC + idx / bnC;
  const int bn = (c8 >> 1) * bnC + idx % bnC;
  const int tid = threadIdx.x;
  const int lane = tid & 63, w = tid >> 6;
  const int wm = w >> 2, wn = w & 3;               // 2M x 4N wave grid
  const int l15 = lane & 15, l16 = lane >> 4;
  const bf16_t* Ag = A + (size_t)bm * 256 * lda;
  const bf16_t* Bg = Bt + (size_t)bn * 256 * K;
  const int NT = K >> 6;

  f32x4 acc[8][4] = {};

  auto stage = [&](int j) {
    const int t = j >> 2, item = j & 3, buf = t & 1;
    bf16_t* dst;
    const bf16_t* src;
    int stride;
    if (item < 2) { dst = &Bs[buf][item * 128][0];
                    src = Bg + (size_t)item * 128 * K;  stride = K;   }
    else          { dst = &As[buf][(item - 2) * 128][0];
                    src = Ag + (size_t)(item - 2) * 128 * lda; stride = lda; }
    const int k0 = t << 6;
#pragma unroll
    for (int i = 0; i < 2; i++) {
      int c = i * 512 + tid;
      int row = c >> 3, q = c & 7;
      int colE = (q ^ (row & 7)) << 3;   // inverse swizzle on global source
      gload_lds16(src + (size_t)row * stride + k0 + colE, dst + c * 8);
    }
  };
  auto frag = [&](const bf16_t* tile, int row, int kk) -> bf16x8 {
    int byte = ((row << 7) + (kk << 6) + (l16 << 4)) ^ ((row & 7) << 4);
    return *(const bf16x8*)((const char*)tile + byte);
  };

  for (int j = 0; j < 7; j++) stage(j);
  asm volatile("s_waitcnt vmcnt(6)" ::: "memory");
  __builtin_amdgcn_s_barrier();

  for (int t = 0; t < NT; t++) {
    const int buf = t & 1;
    const bf16_t* At = &As[buf][0][0];
    const bf16_t* Bc = &Bs[buf][0][0];
    bf16x8 bfrg[4][2];
    const int jb = (t << 2) + 7;
#pragma unroll
    for (int p = 0; p < 4; p++) {
      bf16x8 afrg[2][2];
      if (p == 0) {
#pragma unroll
        for (int ni = 0; ni < 4; ni++)
#pragma unroll
          for (int kk = 0; kk < 2; kk++)
            bfrg[ni][kk] = frag(Bc, wn * 64 + ni * 16 + l15, kk);
      }
#pragma unroll
      for (int mi = 0; mi < 2; mi++)
#pragma unroll
        for (int kk = 0; kk < 2; kk++)
          afrg[mi][kk] = frag(At, wm * 128 + p * 32 + mi * 16 + l15, kk);
      if (jb + p < 4 * NT) stage(jb + p);
      __builtin_amdgcn_sched_barrier(0);
      __builtin_amdgcn_s_barrier();
      asm volatile("s_waitcnt lgkmcnt(0)" ::: "memory");
      __builtin_amdgcn_sched_barrier(0);
      __builtin_amdgcn_s_setprio(1);
#pragma unroll
      for (int mi = 0; mi < 2; mi++)
#pragma unroll
        for (int ni = 0; ni < 4; ni++)
#pragma unroll
          for (int kk = 0; kk < 2; kk++)
            acc[p * 2 + mi][ni] = mfma16(afrg[mi][kk], bfrg[ni][kk],
                                         acc[p * 2 + mi][ni]);
      __builtin_amdgcn_s_setprio(0);
      __builtin_amdgcn_sched_barrier(0);
      if (p == 3) {
        if (t < NT - 2) { asm volatile("s_waitcnt vmcnt(6)" ::: "memory"); }
        else            { asm volatile("s_waitcnt vmcnt(0)" ::: "memory"); }
      }
      __builtin_amdgcn_s_barrier();
    }
  }

  const int r0 = bm * 256 + wm * 128 + (l16 << 2);
  if (FUSE == 0) {
    const int c0 = bn * 256 + wn * 64 + l15;
#pragma unroll
    for (int mi = 0; mi < 8; mi++)
#pragma unroll
      for (int ni = 0; ni < 4; ni++)
#pragma unroll
        for (int r = 0; r < 4; r++)
          C[(size_t)(r0 + mi * 16 + r) * ldc + c0 + ni * 16] =
              __float2bfloat16(acc[mi][ni][r]);
  } else if (FUSE == 1) {
    const int c0 = bn * 128 + wn * 32 + l15;
#pragma unroll
    for (int mi = 0; mi < 8; mi++)
#pragma unroll
      for (int j = 0; j < 2; j++)
#pragma unroll
        for (int r = 0; r < 4; r++) {
          float g = acc[mi][2 * j][r], u = acc[mi][2 * j + 1][r];
          float a = g / (1.f + __expf(-g)) * u;
          C[(size_t)(r0 + mi * 16 + r) * ldc + c0 + j * 16] = __float2bfloat16(a);
        }
  } else {  // FUSE == 2
    const int c0 = bn * 256 + wn * 64 + l15;
    if (bn < 8) {   // q/k: cols < 2048 -> RoPE then store to qkv
#pragma unroll
      for (int mi = 0; mi < 8; mi++)
#pragma unroll
        for (int r = 0; r < 4; r++) {
          const int row = r0 + mi * 16 + r;
          const int tt = row & (S_LEN - 1);
#pragma unroll
          for (int ni = 0; ni < 2; ni++) {
            const int i = ni * 16 + l15;
            const float cz = cosb[tt * HDIM + i];
            const float sz = sinb[tt * HDIM + i];
            const float x1 = acc[mi][ni][r], x2 = acc[mi][ni + 2][r];
            C[(size_t)row * ldc + c0 + ni * 16] =
                __float2bfloat16(x1 * cz - x2 * sz);
            C[(size_t)row * ldc + c0 + (ni + 2) * 16] =
                __float2bfloat16(x2 * cz + x1 * sz);
          }
        }
    } else {        // v section: write vT[(bh*64+dh)*2048 + t] directly
      const int hh = (bn - 8) * 4 + wn;
      const int b = r0 >> 11, t0 = r0 & (S_LEN - 1);
#pragma unroll
      for (int mi = 0; mi < 8; mi++)
#pragma unroll
        for (int ni = 0; ni < 4; ni++) {
          us4 pk;
#pragma unroll
          for (int r = 0; r < 4; r++) pk.v[r] = f2bf(acc[mi][ni][r]);
          *(us4*)&vTout[((size_t)((b << 4) + hh) * 64 + ni * 16 + l15) * S_LEN
                        + t0 + mi * 16] = pk;
        }
    }
  }
}

// ---------------------------------------------------------------------------
// Small-N GEMM: 128M x 64N tile, BK=64, 256 threads / 4 waves (2M x 2N),
// ring-3 LDS (72KB -> 2 independent blocks/CU), depth-2 counted vmcnt
// (6 loads/thread/stage -> vmcnt(6)/vmcnt(0)). One raw s_barrier per iter.
// EPI 0: C bf16 store; EPI 1: Cf (f32) += acc  (fused residual add)
// ---------------------------------------------------------------------------
template <int EPI>
__global__ __launch_bounds__(256) void gemm_sn(
    const bf16_t* __restrict__ A, const bf16_t* __restrict__ Bt,
    bf16_t* __restrict__ Cb, float* __restrict__ Cf, int N, int K, int lda) {
  __shared__ __align__(16) bf16_t As[3][128][64];   // 16KB each
  __shared__ __align__(16) bf16_t Bs[3][64][64];    // 8KB each
  const int nbn = N >> 6;
  const int bid = blockIdx.x;
  const int sbid = (bid & 7) * (gridDim.x >> 3) + (bid >> 3);  // XCD-chunked
  const int bn = sbid % nbn, bm = sbid / nbn;
  const int tid = threadIdx.x, lane = tid & 63, w = tid >> 6;
  const int wm = w >> 1, wn = w & 1;              // 2M x 2N wave grid
  const int l15 = lane & 15, l16 = lane >> 4;
  const bf16_t* Ag = A + (size_t)bm * 128 * lda;
  const bf16_t* Bg = Bt + (size_t)bn * 64 * K;
  f32x4 acc[4][2] = {};
  const int NT = K >> 6;

  // stage: A 16KB (1024 chunks, 4/thread) + B 8KB (512 chunks, 2/thread)
  auto stage = [&](int buf, int t) {
    const int k0 = t << 6;
#pragma unroll
    for (int i = 0; i < 4; i++) {
      int c = i * 256 + tid;
      int row = c >> 3, q = c & 7;
      int colE = (q ^ (row & 7)) << 3;            // inverse swizzle on source
      gload_lds16(Ag + (size_t)row * lda + k0 + colE, &As[buf][0][0] + c * 8);
    }
#pragma unroll
    for (int i = 0; i < 2; i++) {
      int c = i * 256 + tid;
      int row = c >> 3, q = c & 7;
      int colE = (q ^ (row & 7)) << 3;
      gload_lds16(Bg + (size_t)row * K + k0 + colE, &Bs[buf][0][0] + c * 8);
    }
  };
  // swizzled fragment read: kk = K-half (0/1), 16B slot = kk*4 + l16
  auto frag = [&](const bf16_t* base, int row, int kk) -> bf16x8 {
    int byte = ((row << 7) + (kk << 6) + (l16 << 4)) ^ ((row & 7) << 4);
    return *(const bf16x8*)((const char*)base + byte);
  };

  stage(0, 0);
  if (NT > 1) stage(1, 1);
  int bi = 0;
  for (int t = 0; t < NT; t++) {
    if (t + 1 < NT) { asm volatile("s_waitcnt vmcnt(6)" ::: "memory"); }
    else            { asm volatile("s_waitcnt vmcnt(0)" ::: "memory"); }
    __builtin_amdgcn_s_barrier();
    __builtin_amdgcn_sched_barrier(0);
    if (t + 2 < NT) {
      int nb = bi + 2; if (nb >= 3) nb -= 3;
      stage(nb, t + 2);
    }
    __builtin_amdgcn_sched_barrier(0);
    const bf16_t* Ab = &As[bi][0][0];
    const bf16_t* Bb = &Bs[bi][0][0];
    bf16x8 af[4][2], bfr[2][2];
#pragma unroll
    for (int mi = 0; mi < 4; mi++)
#pragma unroll
      for (int kk = 0; kk < 2; kk++)
        af[mi][kk] = frag(Ab, wm * 64 + mi * 16 + l15, kk);
#pragma unroll
    for (int ni = 0; ni < 2; ni++)
#pragma unroll
      for (int kk = 0; kk < 2; kk++)
        bfr[ni][kk] = frag(Bb, wn * 32 + ni * 16 + l15, kk);
    __builtin_amdgcn_s_setprio(1);
#pragma unroll
    for (int mi = 0; mi < 4; mi++)
#pragma unroll
      for (int ni = 0; ni < 2; ni++)
#pragma unroll
        for (int kk = 0; kk < 2; kk++)
          acc[mi][ni] = mfma16(af[mi][kk], bfr[ni][kk], acc[mi][ni]);
    __builtin_amdgcn_s_setprio(0);
    __builtin_amdgcn_sched_barrier(0);   // keep reads+MFMA before next barrier
    bi++; if (bi >= 3) bi -= 3;
  }

  const int r0 = bm * 128 + wm * 64 + (l16 << 2);
  const int c0 = bn * 64 + wn * 32 + l15;
#pragma unroll
  for (int mi = 0; mi < 4; mi++)
#pragma unroll
    for (int ni = 0; ni < 2; ni++)
#pragma unroll
      for (int r = 0; r < 4; r++) {
        size_t off = (size_t)(r0 + mi * 16 + r) * N + c0 + ni * 16;
        if (EPI == 0) Cb[off] = __float2bfloat16(acc[mi][ni][r]);
        else          Cf[off] += acc[mi][ni][r];
      }
}

// ---------------------------------------------------------------------------
// Flash attention (r15/r17 structure, measured best): block = (bh, pair)
// covering 64-row q-tiles {p, 31-p} (exact balance, grid 512 = 2 blocks/CU
// for decoupled TLP). Ring-3 K/V buffers, depth-2 counted vmcnt, one raw
// barrier per step. S^T-swapped QK (per-thread one q = l15, 16 kv):
// in-thread max + 2 shfl softmax; P packed 4xbf16 -> b64 writes; alpha
// redistributed via 4 shfls; row-sum via MFMA ones-column; exp2 softmax.
// [Bracketing: 128-row tiles (r13/r14), no staging (r16), V-in-reg (r18)
// all regressed — this structure is the measured local optimum.]
// ---------------------------------------------------------------------------
__global__ __launch_bounds__(256) void attn_kernel(
    const bf16_t* __restrict__ qkv, const bf16_t* __restrict__ vT,
    bf16_t* __restrict__ o) {
  __shared__ __align__(16) bf16_t Ks[3][64][64];
  __shared__ __align__(16) bf16_t Vs[3][64][64];
  __shared__ __align__(16) bf16_t Ps[64][64];
  const int bid = blockIdx.x;
  const int pair = (bid >> 3) & 15;
  const int bh = (bid & 7) + ((bid >> 7) << 3);
  const int b = bh >> 4, h = bh & 15;
  const int tid = threadIdx.x, lane = tid & 63, w = tid >> 6;
  const int l15 = lane & 15;
  const int kq = (lane >> 4) << 3;
  const int rq = (lane >> 4) << 2;
  const bf16_t* kbase = qkv + (size_t)b * S_LEN * 3072 + 1024 + h * HDIM;
  const bf16_t* vbase = vT + ((size_t)bh * 64) * S_LEN;

  bf16x8 ones;
#pragma unroll
  for (int e = 0; e < 8; e++) ones[e] = (__bf16)1.0f;

#define STAGE(buf, kt) do {                                                    \
    const bf16_t* kg_ = kbase + (size_t)(kt) * 64 * 3072;                      \
    const bf16_t* vg_ = vbase + (kt) * 64;                                     \
    _Pragma("unroll")                                                          \
    for (int i_ = 0; i_ < 2; i_++) {                                           \
      int cb_ = i_ * 256 + w * 64;                                             \
      int c_ = cb_ + lane;                                                     \
      int row_ = c_ >> 3;                                                      \
      int colE_ = ((c_ & 7) ^ (row_ & 7)) << 3;                                \
      gload_lds16(kg_ + (size_t)row_ * 3072 + colE_,                           \
                  &Ks[buf][0][0] + (size_t)cb_ * 8);                           \
      gload_lds16(vg_ + (size_t)row_ * S_LEN + colE_,                          \
                  &Vs[buf][0][0] + (size_t)cb_ * 8);                           \
    }                                                                          \
  } while (0)

  for (int ph = 0; ph < 2; ph++) {
    const int qb = (ph == 0) ? pair : (31 - pair);
    const int nk = qb + 1;
    const int qrow = qb * 64 + w * 16 + l15;
    const bf16_t* qg = qkv + ((size_t)(b * S_LEN + qrow)) * 3072 + h * HDIM;
    bf16x8 aq0 = *(const bf16x8*)(qg + kq);
    bf16x8 aq1 = *(const bf16x8*)(qg + 32 + kq);
    const float qsc = 0.125f * 1.44269504088896340736f;
#pragma unroll
    for (int e = 0; e < 8; e++) {
      aq0[e] = (__bf16)((float)aq0[e] * qsc);
      aq1[e] = (__bf16)((float)aq1[e] * qsc);
    }
    f32x4 oacc[4] = {};
    f32x4 lacc = {0.f, 0.f, 0.f, 0.f};
    float m_s = -1e30f;                 // per-thread q = w*16 + l15
    const int myq = qb * 64 + w * 16 + l15;

    // protect ring buffers from the previous phase's readers (cross-wave)
    __builtin_amdgcn_s_barrier();
    STAGE(0, 0);
    if (nk > 1) STAGE(1, 1);
    int bi = 0;
    for (int kt = 0; kt < nk; kt++) {
      if (kt + 1 < nk) { asm volatile("s_waitcnt vmcnt(4)" ::: "memory"); }
      else             { asm volatile("s_waitcnt vmcnt(0)" ::: "memory"); }
      __builtin_amdgcn_s_barrier();
      __builtin_amdgcn_sched_barrier(0);
      if (kt + 2 < nk) {
        int nb = bi + 2; if (nb >= 3) nb -= 3;
        STAGE(nb, kt + 2);
      }
      __builtin_amdgcn_sched_barrier(0);
      const bf16_t* Kc = &Ks[bi][0][0];
      const bf16_t* Vc = &Vs[bi][0][0];
      // S^T = K Q^T (swapped operands): col = q (l15), row = kv (rq + reg)
      f32x4 st[4];
      __builtin_amdgcn_s_setprio(1);
#pragma unroll
      for (int f = 0; f < 4; f++) {
        bf16x8 bk0 = *(const bf16x8*)swz(Kc, f * 16 + l15, kq);
        bf16x8 bk1 = *(const bf16x8*)swz(Kc, f * 16 + l15, 32 + kq);
        f32x4 t = {};
        t = mfma16(bk0, aq0, t);
        t = mfma16(bk1, aq1, t);
        st[f] = t;
      }
      __builtin_amdgcn_s_setprio(0);
      if (kt == qb) {   // causal: kv_global > q_global -> -inf
#pragma unroll
        for (int f = 0; f < 4; f++) {
          int kvb = kt * 64 + f * 16 + rq;
#pragma unroll
          for (int r = 0; r < 4; r++)
            if (kvb + r > myq) st[f][r] = -1e30f;
        }
      }
      // per-thread row max over 16 kv + 2 shfl across rq-groups
      float mx = -1e30f;
#pragma unroll
      for (int f = 0; f < 4; f++)
#pragma unroll
        for (int r = 0; r < 4; r++) mx = fmaxf(mx, st[f][r]);
      mx = fmaxf(mx, __shfl_xor(mx, 16));
      mx = fmaxf(mx, __shfl_xor(mx, 32));
      const float mn = fmaxf(m_s, mx);
      const float alpha = exp2f(m_s - mn);
      m_s = mn;
#pragma unroll
      for (int f = 0; f < 4; f++)
#pragma unroll
        for (int r = 0; r < 4; r++) st[f][r] = exp2f(st[f][r] - mn);
      // alpha for PV row layout (q = w*16 + rq + r): source lane l15 = rq + r
      float alpr[4];
#pragma unroll
      for (int r = 0; r < 4; r++) alpr[r] = __shfl(alpha, rq + r);
#pragma unroll
      for (int ni = 0; ni < 4; ni++)
#pragma unroll
        for (int r = 0; r < 4; r++) oacc[ni][r] *= alpr[r];
#pragma unroll
      for (int r = 0; r < 4; r++) lacc[r] *= alpr[r];
      // P -> LDS: thread holds 4 consecutive kv at fixed q -> 4 b64 writes
#pragma unroll
      for (int f = 0; f < 4; f++) {
        us4 pk;
#pragma unroll
        for (int r = 0; r < 4; r++) pk.v[r] = f2bf(st[f][r]);
        *(us4*)swz(&Ps[0][0], w * 16 + l15, f * 16 + rq) = pk;
      }
      __builtin_amdgcn_s_setprio(1);
#pragma unroll
      for (int kk2 = 0; kk2 < 2; kk2++) {
        bf16x8 ap = *(const bf16x8*)swz(&Ps[0][0], w * 16 + l15, kk2 * 32 + kq);
        lacc = mfma16(ap, ones, lacc);
#pragma unroll
        for (int ni = 0; ni < 4; ni++) {
          bf16x8 bv = *(const bf16x8*)swz(Vc, ni * 16 + l15, kk2 * 32 + kq);
          oacc[ni] = mfma16(ap, bv, oacc[ni]);
        }
      }
      __builtin_amdgcn_s_setprio(0);
      __builtin_amdgcn_sched_barrier(0);  // keep reads+MFMA before next barrier
      bi++; if (bi >= 3) bi -= 3;
    }
    bf16_t* ob = o + ((size_t)(b * S_LEN + qb * 64 + w * 16 + rq)) * DIM + h * HDIM + l15;
#pragma unroll
    for (int r = 0; r < 4; r++) {
      float inv = 1.0f / lacc[r];
#pragma unroll
      for (int ni = 0; ni < 4; ni++)
        ob[(size_t)r * DIM + ni * 16] = __float2bfloat16(oacc[ni][r] * inv);
    }
  }
#undef STAGE
}

// ---------------------------------------------------------------------------
extern "C" void kernel_launch(void* const* d_in, const int* in_sizes, int n_in,
                              void* d_out, int out_size, void* d_ws, size_t ws_size,
                              hipStream_t stream) {
  (void)in_sizes; (void)n_in; (void)out_size; (void)ws_size;
  const float* x_processed = (const float*)d_in[0];
  const int*   boundaries  = (const int*)d_in[1];
  const int*   counts      = (const int*)d_in[2];
  const float* x_residual  = (const float*)d_in[3];
  const float* cos_t       = (const float*)d_in[4];
  const float* sin_t       = (const float*)d_in[5];
  // d_in[6] = seq_len (constant 2048, compiled in)
  const float* start_emb   = (const float*)d_in[7];
  const float* Wq  = (const float*)d_in[8];
  const float* Wk  = (const float*)d_in[9];
  const float* Wv  = (const float*)d_in[10];
  const float* Wo  = (const float*)d_in[11];
  const float* Wg  = (const float*)d_in[12];
  const float* Wu  = (const float*)d_in[13];
  const float* Wd  = (const float*)d_in[14];
  const float* ln1 = (const float*)d_in[15];
  const float* ln2 = (const float*)d_in[16];
  const float* fnm = (const float*)d_in[17];

  // Workspace layout (120 MB, lifetime-overlapped):
  char* ws = (char*)d_ws;
  const size_t MB = (size_t)1 << 20;
  float*  x      = (float*)(ws);            // 16MB  residual stream f32
  bf16_t* h      = (bf16_t*)(ws + 16 * MB); // 8MB   rms output bf16
  bf16_t* Wqkv_t = (bf16_t*)(ws + 24 * MB); // 6MB   [3072][1024]
  bf16_t* Wo_t   = (bf16_t*)(ws + 30 * MB); // 2MB   [1024][1024]
  bf16_t* Wgu_t  = (bf16_t*)(ws + 32 * MB); // 16MB  B̃[8192][1024] interleaved
  bf16_t* Wd_t   = (bf16_t*)(ws + 48 * MB); // 8MB   [1024][4096]
  char*   Rg     = ws + 56 * MB;            // 64MB shared region
  bf16_t* qkv  = (bf16_t*)(Rg);             // 24MB [4096][3072]
  bf16_t* vT   = (bf16_t*)(Rg + 24 * MB);   // 8MB  [32][64][2048]
  bf16_t* obuf = (bf16_t*)(Rg + 32 * MB);   // 8MB  [4096][1024]
  bf16_t* act  = (bf16_t*)(Rg);             // 32MB [4096][4096] (after attn)

  expand_kernel<<<NROW, 256, 0, stream>>>(x_processed, boundaries, counts,
                                          x_residual, start_emb, x);

  const size_t dd = (size_t)DIM * DIM, df = (size_t)DIM * FDIM;
  for (int l = 0; l < NLAYER; l++) {
    transpose_cast<0><<<dim3(DIM / 32, DIM / 32), 256, 0, stream>>>(Wq + l * dd, Wqkv_t, DIM, DIM);
    transpose_cast<0><<<dim3(DIM / 32, DIM / 32), 256, 0, stream>>>(Wk + l * dd, Wqkv_t + dd, DIM, DIM);
    transpose_cast<0><<<dim3(DIM / 32, DIM / 32), 256, 0, stream>>>(Wv + l * dd, Wqkv_t + 2 * dd, DIM, DIM);
    transpose_cast<0><<<dim3(DIM / 32, DIM / 32), 256, 0, stream>>>(Wo + l * dd, Wo_t, DIM, DIM);
    transpose_cast<1><<<dim3(FDIM / 32, DIM / 32), 256, 0, stream>>>(Wg + l * df, Wgu_t, DIM, FDIM);
    transpose_cast<2><<<dim3(FDIM / 32, DIM / 32), 256, 0, stream>>>(Wu + l * df, Wgu_t, DIM, FDIM);
    transpose_cast<0><<<dim3(DIM / 32, FDIM / 32), 256, 0, stream>>>(Wd + l * df, Wd_t, FDIM, DIM);

    rmsnorm_kernel<0><<<NROW, 256, 0, stream>>>(x, ln1 + l * DIM, h, nullptr);
    gemm_bt256<2><<<(3072 / 256) * (NROW / 256), 512, 0, stream>>>(
        h, Wqkv_t, qkv, 3072, DIM, DIM, 3072 / 256, NROW / 256, cos_t, sin_t, vT);
    attn_kernel<<<512, 256, 0, stream>>>(qkv, vT, obuf);
    gemm_sn<1><<<(DIM / 64) * (NROW / 128), 256, 0, stream>>>(
        obuf, Wo_t, nullptr, x, DIM, DIM, DIM);

    rmsnorm_kernel<0><<<NROW, 256, 0, stream>>>(x, ln2 + l * DIM, h, nullptr);
    gemm_bt256<1><<<(2 * FDIM / 256) * (NROW / 256), 512, 0, stream>>>(
        h, Wgu_t, act, FDIM, DIM, DIM, 2 * FDIM / 256, NROW / 256,
        nullptr, nullptr, nullptr);
    gemm_sn<1><<<(DIM / 64) * (NROW / 128), 256, 0, stream>>>(
        act, Wd_t, nullptr, x, DIM, FDIM, FDIM);
  }
  rmsnorm_kernel<1><<<NROW, 256, 0, stream>>>(x, fnm, nullptr, (float*)d_out);
}

// Round 20
// 570.841 us; speedup vs baseline: 1.0944x; 1.0275x over previous
//
#include <hip/hip_runtime.h>
#include <hip/hip_bf16.h>

// Problem constants (fixed-shape problem)
#define S_LEN  2048
#define NB     2
#define DIM    1024
#define KSEG   256
#define NLAYER 2
#define NHEAD  16
#define HDIM   64
#define FDIM   4096
#define NROW   (NB * S_LEN)   // 4096 token rows

typedef __bf16 bf16x8 __attribute__((ext_vector_type(8)));
typedef float  f32x4  __attribute__((ext_vector_type(4)));
typedef __hip_bfloat16 bf16_t;

struct __align__(8)  us4 { unsigned short v[4]; };
struct __align__(16) us8 { unsigned short v[8]; };

__device__ __forceinline__ unsigned short f2bf(float f) {
  __hip_bfloat16 t = __float2bfloat16(f);
  return __builtin_bit_cast(unsigned short, t);
}
__device__ __forceinline__ float bf2f(unsigned short x) {
  return __bfloat162float(__builtin_bit_cast(__hip_bfloat16, x));
}

// Async global->LDS, 16B per lane. LDS dest must be wave-uniform base; HW
// scatters lane i at base + i*16 (guide §5 / m104).
__device__ __forceinline__ void gload_lds16(const void* g, void* l) {
  __builtin_amdgcn_global_load_lds((__attribute__((address_space(1))) void*)g,
                                   (__attribute__((address_space(3))) void*)l,
                                   16, 0, 0);
}

__device__ __forceinline__ f32x4 mfma16(bf16x8 a, bf16x8 b, f32x4 c) {
  return __builtin_amdgcn_mfma_f32_16x16x32_bf16(a, b, c, 0, 0, 0);
}

// XOR-swizzle accessor for [rows][64] bf16 LDS tiles (128B row stride, T2/G4):
// byte = (r*128 + kElem*2) ^ ((r&7)<<4). Spreads the 16-rows-same-column
// fragment read across 8 distinct 16B slots (residual 2-way = free).
__device__ __forceinline__ bf16_t* swz(bf16_t* base, int r, int kElem) {
  int byte = ((r << 7) + (kElem << 1)) ^ ((r & 7) << 4);
  return (bf16_t*)((char*)base + byte);
}
__device__ __forceinline__ const bf16_t* swz(const bf16_t* base, int r, int kElem) {
  int byte = ((r << 7) + (kElem << 1)) ^ ((r & 7) << 4);
  return (const bf16_t*)((const char*)base + byte);
}

// ---------------------------------------------------------------------------
// ragged repeat-expand + residual add
// ---------------------------------------------------------------------------
__global__ __launch_bounds__(256) void expand_kernel(
    const float* __restrict__ xp, const int* __restrict__ bnd,
    const int* __restrict__ counts, const float* __restrict__ xres,
    const float* __restrict__ semb, float* __restrict__ x) {
  const int bt = blockIdx.x;
  const int b = bt >> 11, t = bt & (S_LEN - 1);
  const int cnt = counts[b];
  const int* bb = bnd + b * KSEG;
  int lo = 0, hi = KSEG;
  while (lo < hi) {
    int mid = (lo + hi) >> 1;
    int v = (mid < cnt) ? bb[mid] : S_LEN;
    if (v < t) lo = mid + 1; else hi = mid;
  }
  const float* src = (lo == 0) ? semb : (xp + ((size_t)b * KSEG + (lo - 1)) * DIM);
  const int tid = threadIdx.x;
  float4 a = ((const float4*)src)[tid];
  float4 r = ((const float4*)(xres + (size_t)bt * DIM))[tid];
  float4 w; w.x = a.x + r.x; w.y = a.y + r.y; w.z = a.z + r.z; w.w = a.w + r.w;
  ((float4*)(x + (size_t)bt * DIM))[tid] = w;
}

// ---------------------------------------------------------------------------
// RMSNorm: out = x * rsqrt(mean(x^2)+eps) * w ; one block per row of 1024
// ---------------------------------------------------------------------------
template <int F32OUT>
__global__ __launch_bounds__(256) void rmsnorm_kernel(
    const float* __restrict__ x, const float* __restrict__ wgt,
    bf16_t* __restrict__ ob, float* __restrict__ of) {
  const int row = blockIdx.x, tid = threadIdx.x;
  const float4 v = ((const float4*)(x + (size_t)row * DIM))[tid];
  float ss = v.x * v.x + v.y * v.y + v.z * v.z + v.w * v.w;
#pragma unroll
  for (int off = 1; off < 64; off <<= 1) ss += __shfl_xor(ss, off);
  __shared__ float red[4];
  if ((tid & 63) == 0) red[tid >> 6] = ss;
  __syncthreads();
  ss = red[0] + red[1] + red[2] + red[3];
  const float r = rsqrtf(ss * (1.0f / DIM) + 1e-5f);
  const float4 wv = ((const float4*)wgt)[tid];
  if (F32OUT) {
    float4 o4; o4.x = v.x * r * wv.x; o4.y = v.y * r * wv.y;
    o4.z = v.z * r * wv.z; o4.w = v.w * r * wv.w;
    ((float4*)(of + (size_t)row * DIM))[tid] = o4;
  } else {
    us4 p;
    p.v[0] = f2bf(v.x * r * wv.x); p.v[1] = f2bf(v.y * r * wv.y);
    p.v[2] = f2bf(v.z * r * wv.z); p.v[3] = f2bf(v.w * r * wv.w);
    ((us4*)(ob + (size_t)row * DIM))[tid] = p;
  }
}

// ---------------------------------------------------------------------------
// Fused weight transpose+cast for ONE layer: all 7 weights in one launch
// (r20: removes 12 launch gaps + drain tails vs 7 separate dispatches).
// Tile body identical to the old transpose_cast (32x33-padded LDS tile).
// Block decode (wave-uniform):
//   [    0, 4096): Wq/Wk/Wv/Wo  1024x1024, 1024 tiles each, mode 0
//   [ 4096,12288): Wg/Wu        1024x4096, 4096 tiles each, gu-interleave
//                  (out row n -> (n>>4)*32 + (n&15) + 16*is_u)
//   [12288,16384): Wd           4096x1024, 4096 tiles, mode 0
// ---------------------------------------------------------------------------
__global__ __launch_bounds__(256) void transpose_all(
    const float* __restrict__ Wq, const float* __restrict__ Wk,
    const float* __restrict__ Wv, const float* __restrict__ Wo,
    const float* __restrict__ Wg, const float* __restrict__ Wu,
    const float* __restrict__ Wd,
    bf16_t* __restrict__ Wqkv_t, bf16_t* __restrict__ Wo_t,
    bf16_t* __restrict__ Wgu_t, bf16_t* __restrict__ Wd_t) {
  __shared__ float tile[32][33];
  const int tx = threadIdx.x & 31, ty = threadIdx.x >> 5;  // 32 x 8
  const int idx = blockIdx.x;
  const float* in;
  bf16_t* out;
  int R, C, bx, by, mode = 0;
  if (idx < 4096) {          // Wq / Wk / Wv / Wo
    const int which = idx >> 10, t = idx & 1023;
    R = 1024; C = 1024;
    bx = t & 31; by = t >> 5;
    if (which == 0)      { in = Wq; out = Wqkv_t; }
    else if (which == 1) { in = Wk; out = Wqkv_t + 1024 * 1024; }
    else if (which == 2) { in = Wv; out = Wqkv_t + 2 * 1024 * 1024; }
    else                 { in = Wo; out = Wo_t; }
  } else if (idx < 12288) {  // Wg (mode 1) / Wu (mode 2) -> interleaved B̃
    const int j = idx - 4096;
    const int which = j >> 12, t = j & 4095;
    R = 1024; C = 4096;
    bx = t & 127; by = t >> 7;
    in = which ? Wu : Wg; out = Wgu_t; mode = which ? 2 : 1;
  } else {                   // Wd
    const int t = idx - 12288;
    R = 4096; C = 1024;
    bx = t & 31; by = t >> 5;
    in = Wd; out = Wd_t;
  }
  const int cb = bx * 32, rb = by * 32;
#pragma unroll
  for (int i = 0; i < 4; i++) {
    int r = ty + i * 8;
    tile[r][tx] = in[(size_t)(rb + r) * C + cb + tx];
  }
  __syncthreads();
#pragma unroll
  for (int i = 0; i < 4; i++) {
    int r = ty + i * 8;
    int n = cb + r;
    int dr = (mode == 0) ? n : (((n >> 4) << 5) + (n & 15) + (mode == 2 ? 16 : 0));
    out[(size_t)dr * R + rb + tx] = __float2bfloat16(tile[tx][r]);
  }
}

// ---------------------------------------------------------------------------
// 256x256 / BK=64 / 8-wave (2Mx4N) 8-phase GEMM, C = A[M,K] @ Bt[N,K]^T.
// m201 template: double-buffered 128KB LDS, T2 XOR-swizzle, counted vmcnt(6)
// at tile boundaries only, two raw barriers per phase, setprio around the
// MFMA cluster, rectangular per-XCD block swizzle.
// FUSE 0: C[r][c] = bf16(acc), ldc = N.
// FUSE 1: B̃ gu-interleaved; writes silu(g)*u (ldc 4096).
// FUSE 2: QKV with fused RoPE on q/k sections (bn<8); v sections (bn>=8)
//         write vT[(bh*64+dh)*2048 + t] DIRECTLY and skip the C store.
// ---------------------------------------------------------------------------
template <int FUSE>
__global__ __launch_bounds__(512, 2) void gemm_bt256(
    const bf16_t* __restrict__ A, const bf16_t* __restrict__ Bt,
    bf16_t* __restrict__ C, int ldc, int K, int lda, int nbn, int nbm,
    const float* __restrict__ cosb, const float* __restrict__ sinb,
    bf16_t* __restrict__ vTout) {
  __shared__ __align__(16) bf16_t As[2][256][64];
  __shared__ __align__(16) bf16_t Bs[2][256][64];
  const int bid = blockIdx.x;
  const int bmC = nbm >> 1, bnC = nbn >> 2;
  const int c8 = bid & 7, idx = bid >> 3;
  const int bm = (c8 & 1) * bmC + idx / bnC;
  const int bn = (c8 >> 1) * bnC + idx % bnC;
  const int tid = threadIdx.x;
  const int lane = tid & 63, w = tid >> 6;
  const int wm = w >> 2, wn = w & 3;               // 2M x 4N wave grid
  const int l15 = lane & 15, l16 = lane >> 4;
  const bf16_t* Ag = A + (size_t)bm * 256 * lda;
  const bf16_t* Bg = Bt + (size_t)bn * 256 * K;
  const int NT = K >> 6;

  f32x4 acc[8][4] = {};

  auto stage = [&](int j) {
    const int t = j >> 2, item = j & 3, buf = t & 1;
    bf16_t* dst;
    const bf16_t* src;
    int stride;
    if (item < 2) { dst = &Bs[buf][item * 128][0];
                    src = Bg + (size_t)item * 128 * K;  stride = K;   }
    else          { dst = &As[buf][(item - 2) * 128][0];
                    src = Ag + (size_t)(item - 2) * 128 * lda; stride = lda; }
    const int k0 = t << 6;
#pragma unroll
    for (int i = 0; i < 2; i++) {
      int c = i * 512 + tid;
      int row = c >> 3, q = c & 7;
      int colE = (q ^ (row & 7)) << 3;   // inverse swizzle on global source
      gload_lds16(src + (size_t)row * stride + k0 + colE, dst + c * 8);
    }
  };
  auto frag = [&](const bf16_t* tile, int row, int kk) -> bf16x8 {
    int byte = ((row << 7) + (kk << 6) + (l16 << 4)) ^ ((row & 7) << 4);
    return *(const bf16x8*)((const char*)tile + byte);
  };

  for (int j = 0; j < 7; j++) stage(j);
  asm volatile("s_waitcnt vmcnt(6)" ::: "memory");
  __builtin_amdgcn_s_barrier();

  for (int t = 0; t < NT; t++) {
    const int buf = t & 1;
    const bf16_t* At = &As[buf][0][0];
    const bf16_t* Bc = &Bs[buf][0][0];
    bf16x8 bfrg[4][2];
    const int jb = (t << 2) + 7;
#pragma unroll
    for (int p = 0; p < 4; p++) {
      bf16x8 afrg[2][2];
      if (p == 0) {
#pragma unroll
        for (int ni = 0; ni < 4; ni++)
#pragma unroll
          for (int kk = 0; kk < 2; kk++)
            bfrg[ni][kk] = frag(Bc, wn * 64 + ni * 16 + l15, kk);
      }
#pragma unroll
      for (int mi = 0; mi < 2; mi++)
#pragma unroll
        for (int kk = 0; kk < 2; kk++)
          afrg[mi][kk] = frag(At, wm * 128 + p * 32 + mi * 16 + l15, kk);
      if (jb + p < 4 * NT) stage(jb + p);
      __builtin_amdgcn_sched_barrier(0);
      __builtin_amdgcn_s_barrier();
      asm volatile("s_waitcnt lgkmcnt(0)" ::: "memory");
      __builtin_amdgcn_sched_barrier(0);
      __builtin_amdgcn_s_setprio(1);
#pragma unroll
      for (int mi = 0; mi < 2; mi++)
#pragma unroll
        for (int ni = 0; ni < 4; ni++)
#pragma unroll
          for (int kk = 0; kk < 2; kk++)
            acc[p * 2 + mi][ni] = mfma16(afrg[mi][kk], bfrg[ni][kk],
                                         acc[p * 2 + mi][ni]);
      __builtin_amdgcn_s_setprio(0);
      __builtin_amdgcn_sched_barrier(0);
      if (p == 3) {
        if (t < NT - 2) { asm volatile("s_waitcnt vmcnt(6)" ::: "memory"); }
        else            { asm volatile("s_waitcnt vmcnt(0)" ::: "memory"); }
      }
      __builtin_amdgcn_s_barrier();
    }
  }

  const int r0 = bm * 256 + wm * 128 + (l16 << 2);
  if (FUSE == 0) {
    const int c0 = bn * 256 + wn * 64 + l15;
#pragma unroll
    for (int mi = 0; mi < 8; mi++)
#pragma unroll
      for (int ni = 0; ni < 4; ni++)
#pragma unroll
        for (int r = 0; r < 4; r++)
          C[(size_t)(r0 + mi * 16 + r) * ldc + c0 + ni * 16] =
              __float2bfloat16(acc[mi][ni][r]);
  } else if (FUSE == 1) {
    const int c0 = bn * 128 + wn * 32 + l15;
#pragma unroll
    for (int mi = 0; mi < 8; mi++)
#pragma unroll
      for (int j = 0; j < 2; j++)
#pragma unroll
        for (int r = 0; r < 4; r++) {
          float g = acc[mi][2 * j][r], u = acc[mi][2 * j + 1][r];
          float a = g / (1.f + __expf(-g)) * u;
          C[(size_t)(r0 + mi * 16 + r) * ldc + c0 + j * 16] = __float2bfloat16(a);
        }
  } else {  // FUSE == 2
    const int c0 = bn * 256 + wn * 64 + l15;
    if (bn < 8) {   // q/k: cols < 2048 -> RoPE then store to qkv
#pragma unroll
      for (int mi = 0; mi < 8; mi++)
#pragma unroll
        for (int r = 0; r < 4; r++) {
          const int row = r0 + mi * 16 + r;
          const int tt = row & (S_LEN - 1);
#pragma unroll
          for (int ni = 0; ni < 2; ni++) {
            const int i = ni * 16 + l15;
            const float cz = cosb[tt * HDIM + i];
            const float sz = sinb[tt * HDIM + i];
            const float x1 = acc[mi][ni][r], x2 = acc[mi][ni + 2][r];
            C[(size_t)row * ldc + c0 + ni * 16] =
                __float2bfloat16(x1 * cz - x2 * sz);
            C[(size_t)row * ldc + c0 + (ni + 2) * 16] =
                __float2bfloat16(x2 * cz + x1 * sz);
          }
        }
    } else {        // v section: write vT[(bh*64+dh)*2048 + t] directly
      const int hh = (bn - 8) * 4 + wn;
      const int b = r0 >> 11, t0 = r0 & (S_LEN - 1);
#pragma unroll
      for (int mi = 0; mi < 8; mi++)
#pragma unroll
        for (int ni = 0; ni < 4; ni++) {
          us4 pk;
#pragma unroll
          for (int r = 0; r < 4; r++) pk.v[r] = f2bf(acc[mi][ni][r]);
          *(us4*)&vTout[((size_t)((b << 4) + hh) * 64 + ni * 16 + l15) * S_LEN
                        + t0 + mi * 16] = pk;
        }
    }
  }
}

// ---------------------------------------------------------------------------
// Small-N GEMM: 128M x 64N tile, BK=64, 256 threads / 4 waves (2M x 2N),
// ring-3 LDS (72KB -> 2 independent blocks/CU), depth-2 counted vmcnt
// (6 loads/thread/stage -> vmcnt(6)/vmcnt(0)). One raw s_barrier per iter.
// EPI 0: C bf16 store; EPI 1: Cf (f32) += acc  (fused residual add)
// ---------------------------------------------------------------------------
template <int EPI>
__global__ __launch_bounds__(256) void gemm_sn(
    const bf16_t* __restrict__ A, const bf16_t* __restrict__ Bt,
    bf16_t* __restrict__ Cb, float* __restrict__ Cf, int N, int K, int lda) {
  __shared__ __align__(16) bf16_t As[3][128][64];   // 16KB each
  __shared__ __align__(16) bf16_t Bs[3][64][64];    // 8KB each
  const int nbn = N >> 6;
  const int bid = blockIdx.x;
  const int sbid = (bid & 7) * (gridDim.x >> 3) + (bid >> 3);  // XCD-chunked
  const int bn = sbid % nbn, bm = sbid / nbn;
  const int tid = threadIdx.x, lane = tid & 63, w = tid >> 6;
  const int wm = w >> 1, wn = w & 1;              // 2M x 2N wave grid
  const int l15 = lane & 15, l16 = lane >> 4;
  const bf16_t* Ag = A + (size_t)bm * 128 * lda;
  const bf16_t* Bg = Bt + (size_t)bn * 64 * K;
  f32x4 acc[4][2] = {};
  const int NT = K >> 6;

  // stage: A 16KB (1024 chunks, 4/thread) + B 8KB (512 chunks, 2/thread)
  auto stage = [&](int buf, int t) {
    const int k0 = t << 6;
#pragma unroll
    for (int i = 0; i < 4; i++) {
      int c = i * 256 + tid;
      int row = c >> 3, q = c & 7;
      int colE = (q ^ (row & 7)) << 3;            // inverse swizzle on source
      gload_lds16(Ag + (size_t)row * lda + k0 + colE, &As[buf][0][0] + c * 8);
    }
#pragma unroll
    for (int i = 0; i < 2; i++) {
      int c = i * 256 + tid;
      int row = c >> 3, q = c & 7;
      int colE = (q ^ (row & 7)) << 3;
      gload_lds16(Bg + (size_t)row * K + k0 + colE, &Bs[buf][0][0] + c * 8);
    }
  };
  // swizzled fragment read: kk = K-half (0/1), 16B slot = kk*4 + l16
  auto frag = [&](const bf16_t* base, int row, int kk) -> bf16x8 {
    int byte = ((row << 7) + (kk << 6) + (l16 << 4)) ^ ((row & 7) << 4);
    return *(const bf16x8*)((const char*)base + byte);
  };

  stage(0, 0);
  if (NT > 1) stage(1, 1);
  int bi = 0;
  for (int t = 0; t < NT; t++) {
    if (t + 1 < NT) { asm volatile("s_waitcnt vmcnt(6)" ::: "memory"); }
    else            { asm volatile("s_waitcnt vmcnt(0)" ::: "memory"); }
    __builtin_amdgcn_s_barrier();
    __builtin_amdgcn_sched_barrier(0);
    if (t + 2 < NT) {
      int nb = bi + 2; if (nb >= 3) nb -= 3;
      stage(nb, t + 2);
    }
    __builtin_amdgcn_sched_barrier(0);
    const bf16_t* Ab = &As[bi][0][0];
    const bf16_t* Bb = &Bs[bi][0][0];
    bf16x8 af[4][2], bfr[2][2];
#pragma unroll
    for (int mi = 0; mi < 4; mi++)
#pragma unroll
      for (int kk = 0; kk < 2; kk++)
        af[mi][kk] = frag(Ab, wm * 64 + mi * 16 + l15, kk);
#pragma unroll
    for (int ni = 0; ni < 2; ni++)
#pragma unroll
      for (int kk = 0; kk < 2; kk++)
        bfr[ni][kk] = frag(Bb, wn * 32 + ni * 16 + l15, kk);
    __builtin_amdgcn_s_setprio(1);
#pragma unroll
    for (int mi = 0; mi < 4; mi++)
#pragma unroll
      for (int ni = 0; ni < 2; ni++)
#pragma unroll
        for (int kk = 0; kk < 2; kk++)
          acc[mi][ni] = mfma16(af[mi][kk], bfr[ni][kk], acc[mi][ni]);
    __builtin_amdgcn_s_setprio(0);
    __builtin_amdgcn_sched_barrier(0);   // keep reads+MFMA before next barrier
    bi++; if (bi >= 3) bi -= 3;
  }

  const int r0 = bm * 128 + wm * 64 + (l16 << 2);
  const int c0 = bn * 64 + wn * 32 + l15;
#pragma unroll
  for (int mi = 0; mi < 4; mi++)
#pragma unroll
    for (int ni = 0; ni < 2; ni++)
#pragma unroll
      for (int r = 0; r < 4; r++) {
        size_t off = (size_t)(r0 + mi * 16 + r) * N + c0 + ni * 16;
        if (EPI == 0) Cb[off] = __float2bfloat16(acc[mi][ni][r]);
        else          Cf[off] += acc[mi][ni][r];
      }
}

// ---------------------------------------------------------------------------
// Flash attention (r15/r17 structure, measured best): block = (bh, pair)
// covering 64-row q-tiles {p, 31-p} (exact balance, grid 512 = 2 blocks/CU
// for decoupled TLP). Ring-3 K/V buffers, depth-2 counted vmcnt, one raw
// barrier per step. S^T-swapped QK (per-thread one q = l15, 16 kv):
// in-thread max + 2 shfl softmax; P packed 4xbf16 -> b64 writes; alpha
// redistributed via 4 shfls; row-sum via MFMA ones-column; exp2 softmax.
// [Bracketing: 128-row tiles (r13/r14), no staging (r16), V-in-reg (r18)
// all regressed — this structure is the measured local optimum.]
// ---------------------------------------------------------------------------
__global__ __launch_bounds__(256) void attn_kernel(
    const bf16_t* __restrict__ qkv, const bf16_t* __restrict__ vT,
    bf16_t* __restrict__ o) {
  __shared__ __align__(16) bf16_t Ks[3][64][64];
  __shared__ __align__(16) bf16_t Vs[3][64][64];
  __shared__ __align__(16) bf16_t Ps[64][64];
  const int bid = blockIdx.x;
  const int pair = (bid >> 3) & 15;
  const int bh = (bid & 7) + ((bid >> 7) << 3);
  const int b = bh >> 4, h = bh & 15;
  const int tid = threadIdx.x, lane = tid & 63, w = tid >> 6;
  const int l15 = lane & 15;
  const int kq = (lane >> 4) << 3;
  const int rq = (lane >> 4) << 2;
  const bf16_t* kbase = qkv + (size_t)b * S_LEN * 3072 + 1024 + h * HDIM;
  const bf16_t* vbase = vT + ((size_t)bh * 64) * S_LEN;

  bf16x8 ones;
#pragma unroll
  for (int e = 0; e < 8; e++) ones[e] = (__bf16)1.0f;

#define STAGE(buf, kt) do {                                                    \
    const bf16_t* kg_ = kbase + (size_t)(kt) * 64 * 3072;                      \
    const bf16_t* vg_ = vbase + (kt) * 64;                                     \
    _Pragma("unroll")                                                          \
    for (int i_ = 0; i_ < 2; i_++) {                                           \
      int cb_ = i_ * 256 + w * 64;                                             \
      int c_ = cb_ + lane;                                                     \
      int row_ = c_ >> 3;                                                      \
      int colE_ = ((c_ & 7) ^ (row_ & 7)) << 3;                                \
      gload_lds16(kg_ + (size_t)row_ * 3072 + colE_,                           \
                  &Ks[buf][0][0] + (size_t)cb_ * 8);                           \
      gload_lds16(vg_ + (size_t)row_ * S_LEN + colE_,                          \
                  &Vs[buf][0][0] + (size_t)cb_ * 8);                           \
    }                                                                          \
  } while (0)

  for (int ph = 0; ph < 2; ph++) {
    const int qb = (ph == 0) ? pair : (31 - pair);
    const int nk = qb + 1;
    const int qrow = qb * 64 + w * 16 + l15;
    const bf16_t* qg = qkv + ((size_t)(b * S_LEN + qrow)) * 3072 + h * HDIM;
    bf16x8 aq0 = *(const bf16x8*)(qg + kq);
    bf16x8 aq1 = *(const bf16x8*)(qg + 32 + kq);
    const float qsc = 0.125f * 1.44269504088896340736f;
#pragma unroll
    for (int e = 0; e < 8; e++) {
      aq0[e] = (__bf16)((float)aq0[e] * qsc);
      aq1[e] = (__bf16)((float)aq1[e] * qsc);
    }
    f32x4 oacc[4] = {};
    f32x4 lacc = {0.f, 0.f, 0.f, 0.f};
    float m_s = -1e30f;                 // per-thread q = w*16 + l15
    const int myq = qb * 64 + w * 16 + l15;

    // protect ring buffers from the previous phase's readers (cross-wave)
    __builtin_amdgcn_s_barrier();
    STAGE(0, 0);
    if (nk > 1) STAGE(1, 1);
    int bi = 0;
    for (int kt = 0; kt < nk; kt++) {
      if (kt + 1 < nk) { asm volatile("s_waitcnt vmcnt(4)" ::: "memory"); }
      else             { asm volatile("s_waitcnt vmcnt(0)" ::: "memory"); }
      __builtin_amdgcn_s_barrier();
      __builtin_amdgcn_sched_barrier(0);
      if (kt + 2 < nk) {
        int nb = bi + 2; if (nb >= 3) nb -= 3;
        STAGE(nb, kt + 2);
      }
      __builtin_amdgcn_sched_barrier(0);
      const bf16_t* Kc = &Ks[bi][0][0];
      const bf16_t* Vc = &Vs[bi][0][0];
      // S^T = K Q^T (swapped operands): col = q (l15), row = kv (rq + reg)
      f32x4 st[4];
      __builtin_amdgcn_s_setprio(1);
#pragma unroll
      for (int f = 0; f < 4; f++) {
        bf16x8 bk0 = *(const bf16x8*)swz(Kc, f * 16 + l15, kq);
        bf16x8 bk1 = *(const bf16x8*)swz(Kc, f * 16 + l15, 32 + kq);
        f32x4 t = {};
        t = mfma16(bk0, aq0, t);
        t = mfma16(bk1, aq1, t);
        st[f] = t;
      }
      __builtin_amdgcn_s_setprio(0);
      if (kt == qb) {   // causal: kv_global > q_global -> -inf
#pragma unroll
        for (int f = 0; f < 4; f++) {
          int kvb = kt * 64 + f * 16 + rq;
#pragma unroll
          for (int r = 0; r < 4; r++)
            if (kvb + r > myq) st[f][r] = -1e30f;
        }
      }
      // per-thread row max over 16 kv + 2 shfl across rq-groups
      float mx = -1e30f;
#pragma unroll
      for (int f = 0; f < 4; f++)
#pragma unroll
        for (int r = 0; r < 4; r++) mx = fmaxf(mx, st[f][r]);
      mx = fmaxf(mx, __shfl_xor(mx, 16));
      mx = fmaxf(mx, __shfl_xor(mx, 32));
      const float mn = fmaxf(m_s, mx);
      const float alpha = exp2f(m_s - mn);
      m_s = mn;
#pragma unroll
      for (int f = 0; f < 4; f++)
#pragma unroll
        for (int r = 0; r < 4; r++) st[f][r] = exp2f(st[f][r] - mn);
      // alpha for PV row layout (q = w*16 + rq + r): source lane l15 = rq + r
      float alpr[4];
#pragma unroll
      for (int r = 0; r < 4; r++) alpr[r] = __shfl(alpha, rq + r);
#pragma unroll
      for (int ni = 0; ni < 4; ni++)
#pragma unroll
        for (int r = 0; r < 4; r++) oacc[ni][r] *= alpr[r];
#pragma unroll
      for (int r = 0; r < 4; r++) lacc[r] *= alpr[r];
      // P -> LDS: thread holds 4 consecutive kv at fixed q -> 4 b64 writes
#pragma unroll
      for (int f = 0; f < 4; f++) {
        us4 pk;
#pragma unroll
        for (int r = 0; r < 4; r++) pk.v[r] = f2bf(st[f][r]);
        *(us4*)swz(&Ps[0][0], w * 16 + l15, f * 16 + rq) = pk;
      }
      __builtin_amdgcn_s_setprio(1);
#pragma unroll
      for (int kk2 = 0; kk2 < 2; kk2++) {
        bf16x8 ap = *(const bf16x8*)swz(&Ps[0][0], w * 16 + l15, kk2 * 32 + kq);
        lacc = mfma16(ap, ones, lacc);
#pragma unroll
        for (int ni = 0; ni < 4; ni++) {
          bf16x8 bv = *(const bf16x8*)swz(Vc, ni * 16 + l15, kk2 * 32 + kq);
          oacc[ni] = mfma16(ap, bv, oacc[ni]);
        }
      }
      __builtin_amdgcn_s_setprio(0);
      __builtin_amdgcn_sched_barrier(0);  // keep reads+MFMA before next barrier
      bi++; if (bi >= 3) bi -= 3;
    }
    bf16_t* ob = o + ((size_t)(b * S_LEN + qb * 64 + w * 16 + rq)) * DIM + h * HDIM + l15;
#pragma unroll
    for (int r = 0; r < 4; r++) {
      float inv = 1.0f / lacc[r];
#pragma unroll
      for (int ni = 0; ni < 4; ni++)
        ob[(size_t)r * DIM + ni * 16] = __float2bfloat16(oacc[ni][r] * inv);
    }
  }
#undef STAGE
}

// ---------------------------------------------------------------------------
extern "C" void kernel_launch(void* const* d_in, const int* in_sizes, int n_in,
                              void* d_out, int out_size, void* d_ws, size_t ws_size,
                              hipStream_t stream) {
  (void)in_sizes; (void)n_in; (void)out_size; (void)ws_size;
  const float* x_processed = (const float*)d_in[0];
  const int*   boundaries  = (const int*)d_in[1];
  const int*   counts      = (const int*)d_in[2];
  const float* x_residual  = (const float*)d_in[3];
  const float* cos_t       = (const float*)d_in[4];
  const float* sin_t       = (const float*)d_in[5];
  // d_in[6] = seq_len (constant 2048, compiled in)
  const float* start_emb   = (const float*)d_in[7];
  const float* Wq  = (const float*)d_in[8];
  const float* Wk  = (const float*)d_in[9];
  const float* Wv  = (const float*)d_in[10];
  const float* Wo  = (const float*)d_in[11];
  const float* Wg  = (const float*)d_in[12];
  const float* Wu  = (const float*)d_in[13];
  const float* Wd  = (const float*)d_in[14];
  const float* ln1 = (const float*)d_in[15];
  const float* ln2 = (const float*)d_in[16];
  const float* fnm = (const float*)d_in[17];

  // Workspace layout (120 MB, lifetime-overlapped):
  char* ws = (char*)d_ws;
  const size_t MB = (size_t)1 << 20;
  float*  x      = (float*)(ws);            // 16MB  residual stream f32
  bf16_t* h      = (bf16_t*)(ws + 16 * MB); // 8MB   rms output bf16
  bf16_t* Wqkv_t = (bf16_t*)(ws + 24 * MB); // 6MB   [3072][1024]
  bf16_t* Wo_t   = (bf16_t*)(ws + 30 * MB); // 2MB   [1024][1024]
  bf16_t* Wgu_t  = (bf16_t*)(ws + 32 * MB); // 16MB  B̃[8192][1024] interleaved
  bf16_t* Wd_t   = (bf16_t*)(ws + 48 * MB); // 8MB   [1024][4096]
  char*   Rg     = ws + 56 * MB;            // 64MB shared region
  bf16_t* qkv  = (bf16_t*)(Rg);             // 24MB [4096][3072]
  bf16_t* vT   = (bf16_t*)(Rg + 24 * MB);   // 8MB  [32][64][2048]
  bf16_t* obuf = (bf16_t*)(Rg + 32 * MB);   // 8MB  [4096][1024]
  bf16_t* act  = (bf16_t*)(Rg);             // 32MB [4096][4096] (after attn)

  expand_kernel<<<NROW, 256, 0, stream>>>(x_processed, boundaries, counts,
                                          x_residual, start_emb, x);

  const size_t dd = (size_t)DIM * DIM, df = (size_t)DIM * FDIM;
  for (int l = 0; l < NLAYER; l++) {
    transpose_all<<<16384, 256, 0, stream>>>(
        Wq + l * dd, Wk + l * dd, Wv + l * dd, Wo + l * dd,
        Wg + l * df, Wu + l * df, Wd + l * df,
        Wqkv_t, Wo_t, Wgu_t, Wd_t);

    rmsnorm_kernel<0><<<NROW, 256, 0, stream>>>(x, ln1 + l * DIM, h, nullptr);
    gemm_bt256<2><<<(3072 / 256) * (NROW / 256), 512, 0, stream>>>(
        h, Wqkv_t, qkv, 3072, DIM, DIM, 3072 / 256, NROW / 256, cos_t, sin_t, vT);
    attn_kernel<<<512, 256, 0, stream>>>(qkv, vT, obuf);
    gemm_sn<1><<<(DIM / 64) * (NROW / 128), 256, 0, stream>>>(
        obuf, Wo_t, nullptr, x, DIM, DIM, DIM);

    rmsnorm_kernel<0><<<NROW, 256, 0, stream>>>(x, ln2 + l * DIM, h, nullptr);
    gemm_bt256<1><<<(2 * FDIM / 256) * (NROW / 256), 512, 0, stream>>>(
        h, Wgu_t, act, FDIM, DIM, DIM, 2 * FDIM / 256, NROW / 256,
        nullptr, nullptr, nullptr);
    gemm_sn<1><<<(DIM / 64) * (NROW / 128), 256, 0, stream>>>(
        act, Wd_t, nullptr, x, DIM, FDIM, FDIM);
  }
  rmsnorm_kernel<1><<<NROW, 256, 0, stream>>>(x, fnm, nullptr, (float*)d_out);
}

// Round 21
// 565.354 us; speedup vs baseline: 1.1051x; 1.0097x over previous
//
#include <hip/hip_runtime.h>
#include <hip/hip_bf16.h>

// Problem constants (fixed-shape problem)
#define S_LEN  2048
#define NB     2
#define DIM    1024
#define KSEG   256
#define NLAYER 2
#define NHEAD  16
#define HDIM   64
#define FDIM   4096
#define NROW   (NB * S_LEN)   // 4096 token rows

typedef __bf16 bf16x8 __attribute__((ext_vector_type(8)));
typedef float  f32x4  __attribute__((ext_vector_type(4)));
typedef __hip_bfloat16 bf16_t;

struct __align__(8)  us4 { unsigned short v[4]; };
struct __align__(16) us8 { unsigned short v[8]; };

__device__ __forceinline__ unsigned short f2bf(float f) {
  __hip_bfloat16 t = __float2bfloat16(f);
  return __builtin_bit_cast(unsigned short, t);
}
__device__ __forceinline__ float bf2f(unsigned short x) {
  return __bfloat162float(__builtin_bit_cast(__hip_bfloat16, x));
}

// Async global->LDS, 16B per lane. LDS dest must be wave-uniform base; HW
// scatters lane i at base + i*16 (guide §5 / m104).
__device__ __forceinline__ void gload_lds16(const void* g, void* l) {
  __builtin_amdgcn_global_load_lds((__attribute__((address_space(1))) void*)g,
                                   (__attribute__((address_space(3))) void*)l,
                                   16, 0, 0);
}

__device__ __forceinline__ f32x4 mfma16(bf16x8 a, bf16x8 b, f32x4 c) {
  return __builtin_amdgcn_mfma_f32_16x16x32_bf16(a, b, c, 0, 0, 0);
}

// XOR-swizzle accessor for [rows][64] bf16 LDS tiles (128B row stride, T2/G4):
// byte = (r*128 + kElem*2) ^ ((r&7)<<4). Spreads the 16-rows-same-column
// fragment read across 8 distinct 16B slots (residual 2-way = free).
__device__ __forceinline__ bf16_t* swz(bf16_t* base, int r, int kElem) {
  int byte = ((r << 7) + (kElem << 1)) ^ ((r & 7) << 4);
  return (bf16_t*)((char*)base + byte);
}
__device__ __forceinline__ const bf16_t* swz(const bf16_t* base, int r, int kElem) {
  int byte = ((r << 7) + (kElem << 1)) ^ ((r & 7) << 4);
  return (const bf16_t*)((const char*)base + byte);
}

// ---------------------------------------------------------------------------
// RMSNorm: out = x * rsqrt(mean(x^2)+eps) * w ; one block per row of 1024
// ---------------------------------------------------------------------------
template <int F32OUT>
__global__ __launch_bounds__(256) void rmsnorm_kernel(
    const float* __restrict__ x, const float* __restrict__ wgt,
    bf16_t* __restrict__ ob, float* __restrict__ of) {
  const int row = blockIdx.x, tid = threadIdx.x;
  const float4 v = ((const float4*)(x + (size_t)row * DIM))[tid];
  float ss = v.x * v.x + v.y * v.y + v.z * v.z + v.w * v.w;
#pragma unroll
  for (int off = 1; off < 64; off <<= 1) ss += __shfl_xor(ss, off);
  __shared__ float red[4];
  if ((tid & 63) == 0) red[tid >> 6] = ss;
  __syncthreads();
  ss = red[0] + red[1] + red[2] + red[3];
  const float r = rsqrtf(ss * (1.0f / DIM) + 1e-5f);
  const float4 wv = ((const float4*)wgt)[tid];
  if (F32OUT) {
    float4 o4; o4.x = v.x * r * wv.x; o4.y = v.y * r * wv.y;
    o4.z = v.z * r * wv.z; o4.w = v.w * r * wv.w;
    ((float4*)(of + (size_t)row * DIM))[tid] = o4;
  } else {
    us4 p;
    p.v[0] = f2bf(v.x * r * wv.x); p.v[1] = f2bf(v.y * r * wv.y);
    p.v[2] = f2bf(v.z * r * wv.z); p.v[3] = f2bf(v.w * r * wv.w);
    ((us4*)(ob + (size_t)row * DIM))[tid] = p;
  }
}

// ---------------------------------------------------------------------------
// Fused weight transpose+cast for ONE layer (all 7 weights) + optionally the
// ragged expand (r21: folds the expand_kernel launch into layer-0's dispatch).
// Tile body identical to the proven transpose_cast (32x33-padded LDS tile).
// Block decode (wave-uniform):
//   [    0, 4096): Wq/Wk/Wv/Wo  1024x1024, 1024 tiles each, mode 0
//   [ 4096,12288): Wg/Wu        1024x4096, 4096 tiles each, gu-interleave
//                  (out row n -> (n>>4)*32 + (n&15) + 16*is_u)
//   [12288,16384): Wd           4096x1024, 4096 tiles, mode 0
//   [16384,16384+nexp): ragged expand + residual add (row = idx-16384)
// ---------------------------------------------------------------------------
__global__ __launch_bounds__(256) void transpose_all(
    const float* __restrict__ Wq, const float* __restrict__ Wk,
    const float* __restrict__ Wv, const float* __restrict__ Wo,
    const float* __restrict__ Wg, const float* __restrict__ Wu,
    const float* __restrict__ Wd,
    bf16_t* __restrict__ Wqkv_t, bf16_t* __restrict__ Wo_t,
    bf16_t* __restrict__ Wgu_t, bf16_t* __restrict__ Wd_t,
    const float* __restrict__ xp, const int* __restrict__ bnd,
    const int* __restrict__ counts, const float* __restrict__ xres,
    const float* __restrict__ semb, float* __restrict__ x) {
  __shared__ float tile[32][33];
  const int tx = threadIdx.x & 31, ty = threadIdx.x >> 5;  // 32 x 8
  const int idx = blockIdx.x;
  if (idx >= 16384) {        // ragged expand + residual add (layer 0 only)
    const int bt = idx - 16384;
    const int b = bt >> 11, t = bt & (S_LEN - 1);
    const int cnt = counts[b];
    const int* bb = bnd + b * KSEG;
    int lo = 0, hi = KSEG;
    while (lo < hi) {
      int mid = (lo + hi) >> 1;
      int v = (mid < cnt) ? bb[mid] : S_LEN;
      if (v < t) lo = mid + 1; else hi = mid;
    }
    const float* src = (lo == 0) ? semb
                                 : (xp + ((size_t)b * KSEG + (lo - 1)) * DIM);
    const int tid = threadIdx.x;
    float4 a = ((const float4*)src)[tid];
    float4 r = ((const float4*)(xres + (size_t)bt * DIM))[tid];
    float4 w; w.x = a.x + r.x; w.y = a.y + r.y; w.z = a.z + r.z; w.w = a.w + r.w;
    ((float4*)(x + (size_t)bt * DIM))[tid] = w;
    return;
  }
  const float* in;
  bf16_t* out;
  int R, C, bx, by, mode = 0;
  if (idx < 4096) {          // Wq / Wk / Wv / Wo
    const int which = idx >> 10, t = idx & 1023;
    R = 1024; C = 1024;
    bx = t & 31; by = t >> 5;
    if (which == 0)      { in = Wq; out = Wqkv_t; }
    else if (which == 1) { in = Wk; out = Wqkv_t + 1024 * 1024; }
    else if (which == 2) { in = Wv; out = Wqkv_t + 2 * 1024 * 1024; }
    else                 { in = Wo; out = Wo_t; }
  } else if (idx < 12288) {  // Wg (mode 1) / Wu (mode 2) -> interleaved B̃
    const int j = idx - 4096;
    const int which = j >> 12, t = j & 4095;
    R = 1024; C = 4096;
    bx = t & 127; by = t >> 7;
    in = which ? Wu : Wg; out = Wgu_t; mode = which ? 2 : 1;
  } else {                   // Wd
    const int t = idx - 12288;
    R = 4096; C = 1024;
    bx = t & 31; by = t >> 5;
    in = Wd; out = Wd_t;
  }
  const int cb = bx * 32, rb = by * 32;
#pragma unroll
  for (int i = 0; i < 4; i++) {
    int r = ty + i * 8;
    tile[r][tx] = in[(size_t)(rb + r) * C + cb + tx];
  }
  __syncthreads();
#pragma unroll
  for (int i = 0; i < 4; i++) {
    int r = ty + i * 8;
    int n = cb + r;
    int dr = (mode == 0) ? n : (((n >> 4) << 5) + (n & 15) + (mode == 2 ? 16 : 0));
    out[(size_t)dr * R + rb + tx] = __float2bfloat16(tile[tx][r]);
  }
}

// ---------------------------------------------------------------------------
// 256x256 / BK=64 / 8-wave (2Mx4N) 8-phase GEMM, C = A[M,K] @ Bt[N,K]^T.
// m201 template: double-buffered 128KB LDS, T2 XOR-swizzle, counted vmcnt(6)
// at tile boundaries only, two raw barriers per phase, setprio around the
// MFMA cluster, rectangular per-XCD block swizzle.
// FUSE 0: C[r][c] = bf16(acc), ldc = N.
// FUSE 1: B̃ gu-interleaved; writes silu(g)*u (ldc 4096).
// FUSE 2: QKV with fused RoPE on q/k sections (bn<8); v sections (bn>=8)
//         write vT[(bh*64+dh)*2048 + t] DIRECTLY and skip the C store.
// ---------------------------------------------------------------------------
template <int FUSE>
__global__ __launch_bounds__(512, 2) void gemm_bt256(
    const bf16_t* __restrict__ A, const bf16_t* __restrict__ Bt,
    bf16_t* __restrict__ C, int ldc, int K, int lda, int nbn, int nbm,
    const float* __restrict__ cosb, const float* __restrict__ sinb,
    bf16_t* __restrict__ vTout) {
  __shared__ __align__(16) bf16_t As[2][256][64];
  __shared__ __align__(16) bf16_t Bs[2][256][64];
  const int bid = blockIdx.x;
  const int bmC = nbm >> 1, bnC = nbn >> 2;
  const int c8 = bid & 7, idx = bid >> 3;
  const int bm = (c8 & 1) * bmC + idx / bnC;
  const int bn = (c8 >> 1) * bnC + idx % bnC;
  const int tid = threadIdx.x;
  const int lane = tid & 63, w = tid >> 6;
  const int wm = w >> 2, wn = w & 3;               // 2M x 4N wave grid
  const int l15 = lane & 15, l16 = lane >> 4;
  const bf16_t* Ag = A + (size_t)bm * 256 * lda;
  const bf16_t* Bg = Bt + (size_t)bn * 256 * K;
  const int NT = K >> 6;

  f32x4 acc[8][4] = {};

  auto stage = [&](int j) {
    const int t = j >> 2, item = j & 3, buf = t & 1;
    bf16_t* dst;
    const bf16_t* src;
    int stride;
    if (item < 2) { dst = &Bs[buf][item * 128][0];
                    src = Bg + (size_t)item * 128 * K;  stride = K;   }
    else          { dst = &As[buf][(item - 2) * 128][0];
                    src = Ag + (size_t)(item - 2) * 128 * lda; stride = lda; }
    const int k0 = t << 6;
#pragma unroll
    for (int i = 0; i < 2; i++) {
      int c = i * 512 + tid;
      int row = c >> 3, q = c & 7;
      int colE = (q ^ (row & 7)) << 3;   // inverse swizzle on global source
      gload_lds16(src + (size_t)row * stride + k0 + colE, dst + c * 8);
    }
  };
  auto frag = [&](const bf16_t* tile, int row, int kk) -> bf16x8 {
    int byte = ((row << 7) + (kk << 6) + (l16 << 4)) ^ ((row & 7) << 4);
    return *(const bf16x8*)((const char*)tile + byte);
  };

  for (int j = 0; j < 7; j++) stage(j);
  asm volatile("s_waitcnt vmcnt(6)" ::: "memory");
  __builtin_amdgcn_s_barrier();

  for (int t = 0; t < NT; t++) {
    const int buf = t & 1;
    const bf16_t* At = &As[buf][0][0];
    const bf16_t* Bc = &Bs[buf][0][0];
    bf16x8 bfrg[4][2];
    const int jb = (t << 2) + 7;
#pragma unroll
    for (int p = 0; p < 4; p++) {
      bf16x8 afrg[2][2];
      if (p == 0) {
#pragma unroll
        for (int ni = 0; ni < 4; ni++)
#pragma unroll
          for (int kk = 0; kk < 2; kk++)
            bfrg[ni][kk] = frag(Bc, wn * 64 + ni * 16 + l15, kk);
      }
#pragma unroll
      for (int mi = 0; mi < 2; mi++)
#pragma unroll
        for (int kk = 0; kk < 2; kk++)
          afrg[mi][kk] = frag(At, wm * 128 + p * 32 + mi * 16 + l15, kk);
      if (jb + p < 4 * NT) stage(jb + p);
      __builtin_amdgcn_sched_barrier(0);
      __builtin_amdgcn_s_barrier();
      asm volatile("s_waitcnt lgkmcnt(0)" ::: "memory");
      __builtin_amdgcn_sched_barrier(0);
      __builtin_amdgcn_s_setprio(1);
#pragma unroll
      for (int mi = 0; mi < 2; mi++)
#pragma unroll
        for (int ni = 0; ni < 4; ni++)
#pragma unroll
          for (int kk = 0; kk < 2; kk++)
            acc[p * 2 + mi][ni] = mfma16(afrg[mi][kk], bfrg[ni][kk],
                                         acc[p * 2 + mi][ni]);
      __builtin_amdgcn_s_setprio(0);
      __builtin_amdgcn_sched_barrier(0);
      if (p == 3) {
        if (t < NT - 2) { asm volatile("s_waitcnt vmcnt(6)" ::: "memory"); }
        else            { asm volatile("s_waitcnt vmcnt(0)" ::: "memory"); }
      }
      __builtin_amdgcn_s_barrier();
    }
  }

  const int r0 = bm * 256 + wm * 128 + (l16 << 2);
  if (FUSE == 0) {
    const int c0 = bn * 256 + wn * 64 + l15;
#pragma unroll
    for (int mi = 0; mi < 8; mi++)
#pragma unroll
      for (int ni = 0; ni < 4; ni++)
#pragma unroll
        for (int r = 0; r < 4; r++)
          C[(size_t)(r0 + mi * 16 + r) * ldc + c0 + ni * 16] =
              __float2bfloat16(acc[mi][ni][r]);
  } else if (FUSE == 1) {
    const int c0 = bn * 128 + wn * 32 + l15;
#pragma unroll
    for (int mi = 0; mi < 8; mi++)
#pragma unroll
      for (int j = 0; j < 2; j++)
#pragma unroll
        for (int r = 0; r < 4; r++) {
          float g = acc[mi][2 * j][r], u = acc[mi][2 * j + 1][r];
          float a = g / (1.f + __expf(-g)) * u;
          C[(size_t)(r0 + mi * 16 + r) * ldc + c0 + j * 16] = __float2bfloat16(a);
        }
  } else {  // FUSE == 2
    const int c0 = bn * 256 + wn * 64 + l15;
    if (bn < 8) {   // q/k: cols < 2048 -> RoPE then store to qkv
#pragma unroll
      for (int mi = 0; mi < 8; mi++)
#pragma unroll
        for (int r = 0; r < 4; r++) {
          const int row = r0 + mi * 16 + r;
          const int tt = row & (S_LEN - 1);
#pragma unroll
          for (int ni = 0; ni < 2; ni++) {
            const int i = ni * 16 + l15;
            const float cz = cosb[tt * HDIM + i];
            const float sz = sinb[tt * HDIM + i];
            const float x1 = acc[mi][ni][r], x2 = acc[mi][ni + 2][r];
            C[(size_t)row * ldc + c0 + ni * 16] =
                __float2bfloat16(x1 * cz - x2 * sz);
            C[(size_t)row * ldc + c0 + (ni + 2) * 16] =
                __float2bfloat16(x2 * cz + x1 * sz);
          }
        }
    } else {        // v section: write vT[(bh*64+dh)*2048 + t] directly
      const int hh = (bn - 8) * 4 + wn;
      const int b = r0 >> 11, t0 = r0 & (S_LEN - 1);
#pragma unroll
      for (int mi = 0; mi < 8; mi++)
#pragma unroll
        for (int ni = 0; ni < 4; ni++) {
          us4 pk;
#pragma unroll
          for (int r = 0; r < 4; r++) pk.v[r] = f2bf(acc[mi][ni][r]);
          *(us4*)&vTout[((size_t)((b << 4) + hh) * 64 + ni * 16 + l15) * S_LEN
                        + t0 + mi * 16] = pk;
        }
    }
  }
}

// ---------------------------------------------------------------------------
// Small-N GEMM: 128M x 64N tile, BK=64, 256 threads / 4 waves (2M x 2N),
// ring-3 LDS (72KB -> 2 independent blocks/CU), depth-2 counted vmcnt
// (6 loads/thread/stage -> vmcnt(6)/vmcnt(0)). One raw s_barrier per iter.
// EPI 0: C bf16 store; EPI 1: Cf (f32) += acc  (fused residual add)
// ---------------------------------------------------------------------------
template <int EPI>
__global__ __launch_bounds__(256) void gemm_sn(
    const bf16_t* __restrict__ A, const bf16_t* __restrict__ Bt,
    bf16_t* __restrict__ Cb, float* __restrict__ Cf, int N, int K, int lda) {
  __shared__ __align__(16) bf16_t As[3][128][64];   // 16KB each
  __shared__ __align__(16) bf16_t Bs[3][64][64];    // 8KB each
  const int nbn = N >> 6;
  const int bid = blockIdx.x;
  const int sbid = (bid & 7) * (gridDim.x >> 3) + (bid >> 3);  // XCD-chunked
  const int bn = sbid % nbn, bm = sbid / nbn;
  const int tid = threadIdx.x, lane = tid & 63, w = tid >> 6;
  const int wm = w >> 1, wn = w & 1;              // 2M x 2N wave grid
  const int l15 = lane & 15, l16 = lane >> 4;
  const bf16_t* Ag = A + (size_t)bm * 128 * lda;
  const bf16_t* Bg = Bt + (size_t)bn * 64 * K;
  f32x4 acc[4][2] = {};
  const int NT = K >> 6;

  // stage: A 16KB (1024 chunks, 4/thread) + B 8KB (512 chunks, 2/thread)
  auto stage = [&](int buf, int t) {
    const int k0 = t << 6;
#pragma unroll
    for (int i = 0; i < 4; i++) {
      int c = i * 256 + tid;
      int row = c >> 3, q = c & 7;
      int colE = (q ^ (row & 7)) << 3;            // inverse swizzle on source
      gload_lds16(Ag + (size_t)row * lda + k0 + colE, &As[buf][0][0] + c * 8);
    }
#pragma unroll
    for (int i = 0; i < 2; i++) {
      int c = i * 256 + tid;
      int row = c >> 3, q = c & 7;
      int colE = (q ^ (row & 7)) << 3;
      gload_lds16(Bg + (size_t)row * K + k0 + colE, &Bs[buf][0][0] + c * 8);
    }
  };
  // swizzled fragment read: kk = K-half (0/1), 16B slot = kk*4 + l16
  auto frag = [&](const bf16_t* base, int row, int kk) -> bf16x8 {
    int byte = ((row << 7) + (kk << 6) + (l16 << 4)) ^ ((row & 7) << 4);
    return *(const bf16x8*)((const char*)base + byte);
  };

  stage(0, 0);
  if (NT > 1) stage(1, 1);
  int bi = 0;
  for (int t = 0; t < NT; t++) {
    if (t + 1 < NT) { asm volatile("s_waitcnt vmcnt(6)" ::: "memory"); }
    else            { asm volatile("s_waitcnt vmcnt(0)" ::: "memory"); }
    __builtin_amdgcn_s_barrier();
    __builtin_amdgcn_sched_barrier(0);
    if (t + 2 < NT) {
      int nb = bi + 2; if (nb >= 3) nb -= 3;
      stage(nb, t + 2);
    }
    __builtin_amdgcn_sched_barrier(0);
    const bf16_t* Ab = &As[bi][0][0];
    const bf16_t* Bb = &Bs[bi][0][0];
    bf16x8 af[4][2], bfr[2][2];
#pragma unroll
    for (int mi = 0; mi < 4; mi++)
#pragma unroll
      for (int kk = 0; kk < 2; kk++)
        af[mi][kk] = frag(Ab, wm * 64 + mi * 16 + l15, kk);
#pragma unroll
    for (int ni = 0; ni < 2; ni++)
#pragma unroll
      for (int kk = 0; kk < 2; kk++)
        bfr[ni][kk] = frag(Bb, wn * 32 + ni * 16 + l15, kk);
    __builtin_amdgcn_s_setprio(1);
#pragma unroll
    for (int mi = 0; mi < 4; mi++)
#pragma unroll
      for (int ni = 0; ni < 2; ni++)
#pragma unroll
        for (int kk = 0; kk < 2; kk++)
          acc[mi][ni] = mfma16(af[mi][kk], bfr[ni][kk], acc[mi][ni]);
    __builtin_amdgcn_s_setprio(0);
    __builtin_amdgcn_sched_barrier(0);   // keep reads+MFMA before next barrier
    bi++; if (bi >= 3) bi -= 3;
  }

  const int r0 = bm * 128 + wm * 64 + (l16 << 2);
  const int c0 = bn * 64 + wn * 32 + l15;
#pragma unroll
  for (int mi = 0; mi < 4; mi++)
#pragma unroll
    for (int ni = 0; ni < 2; ni++)
#pragma unroll
      for (int r = 0; r < 4; r++) {
        size_t off = (size_t)(r0 + mi * 16 + r) * N + c0 + ni * 16;
        if (EPI == 0) Cb[off] = __float2bfloat16(acc[mi][ni][r]);
        else          Cf[off] += acc[mi][ni][r];
      }
}

// ---------------------------------------------------------------------------
// Flash attention (r15/r17 structure, measured best): block = (bh, pair)
// covering 64-row q-tiles {p, 31-p} (exact balance, grid 512 = 2 blocks/CU
// for decoupled TLP). Ring-3 K/V buffers, depth-2 counted vmcnt, one raw
// barrier per step. S^T-swapped QK (per-thread one q = l15, 16 kv):
// in-thread max + 2 shfl softmax; P packed 4xbf16 -> b64 writes; alpha
// redistributed via 4 shfls; row-sum via MFMA ones-column; exp2 softmax.
// [Bracketing: 128-row tiles (r13/r14), no staging (r16), V-in-reg (r18)
// all regressed — this structure is the measured local optimum.]
// ---------------------------------------------------------------------------
__global__ __launch_bounds__(256) void attn_kernel(
    const bf16_t* __restrict__ qkv, const bf16_t* __restrict__ vT,
    bf16_t* __restrict__ o) {
  __shared__ __align__(16) bf16_t Ks[3][64][64];
  __shared__ __align__(16) bf16_t Vs[3][64][64];
  __shared__ __align__(16) bf16_t Ps[64][64];
  const int bid = blockIdx.x;
  const int pair = (bid >> 3) & 15;
  const int bh = (bid & 7) + ((bid >> 7) << 3);
  const int b = bh >> 4, h = bh & 15;
  const int tid = threadIdx.x, lane = tid & 63, w = tid >> 6;
  const int l15 = lane & 15;
  const int kq = (lane >> 4) << 3;
  const int rq = (lane >> 4) << 2;
  const bf16_t* kbase = qkv + (size_t)b * S_LEN * 3072 + 1024 + h * HDIM;
  const bf16_t* vbase = vT + ((size_t)bh * 64) * S_LEN;

  bf16x8 ones;
#pragma unroll
  for (int e = 0; e < 8; e++) ones[e] = (__bf16)1.0f;

#define STAGE(buf, kt) do {                                                    \
    const bf16_t* kg_ = kbase + (size_t)(kt) * 64 * 3072;                      \
    const bf16_t* vg_ = vbase + (kt) * 64;                                     \
    _Pragma("unroll")                                                          \
    for (int i_ = 0; i_ < 2; i_++) {                                           \
      int cb_ = i_ * 256 + w * 64;                                             \
      int c_ = cb_ + lane;                                                     \
      int row_ = c_ >> 3;                                                      \
      int colE_ = ((c_ & 7) ^ (row_ & 7)) << 3;                                \
      gload_lds16(kg_ + (size_t)row_ * 3072 + colE_,                           \
                  &Ks[buf][0][0] + (size_t)cb_ * 8);                           \
      gload_lds16(vg_ + (size_t)row_ * S_LEN + colE_,                          \
                  &Vs[buf][0][0] + (size_t)cb_ * 8);                           \
    }                                                                          \
  } while (0)

  for (int ph = 0; ph < 2; ph++) {
    const int qb = (ph == 0) ? pair : (31 - pair);
    const int nk = qb + 1;
    const int qrow = qb * 64 + w * 16 + l15;
    const bf16_t* qg = qkv + ((size_t)(b * S_LEN + qrow)) * 3072 + h * HDIM;
    bf16x8 aq0 = *(const bf16x8*)(qg + kq);
    bf16x8 aq1 = *(const bf16x8*)(qg + 32 + kq);
    const float qsc = 0.125f * 1.44269504088896340736f;
#pragma unroll
    for (int e = 0; e < 8; e++) {
      aq0[e] = (__bf16)((float)aq0[e] * qsc);
      aq1[e] = (__bf16)((float)aq1[e] * qsc);
    }
    f32x4 oacc[4] = {};
    f32x4 lacc = {0.f, 0.f, 0.f, 0.f};
    float m_s = -1e30f;                 // per-thread q = w*16 + l15
    const int myq = qb * 64 + w * 16 + l15;

    // protect ring buffers from the previous phase's readers (cross-wave)
    __builtin_amdgcn_s_barrier();
    STAGE(0, 0);
    if (nk > 1) STAGE(1, 1);
    int bi = 0;
    for (int kt = 0; kt < nk; kt++) {
      if (kt + 1 < nk) { asm volatile("s_waitcnt vmcnt(4)" ::: "memory"); }
      else             { asm volatile("s_waitcnt vmcnt(0)" ::: "memory"); }
      __builtin_amdgcn_s_barrier();
      __builtin_amdgcn_sched_barrier(0);
      if (kt + 2 < nk) {
        int nb = bi + 2; if (nb >= 3) nb -= 3;
        STAGE(nb, kt + 2);
      }
      __builtin_amdgcn_sched_barrier(0);
      const bf16_t* Kc = &Ks[bi][0][0];
      const bf16_t* Vc = &Vs[bi][0][0];
      // S^T = K Q^T (swapped operands): col = q (l15), row = kv (rq + reg)
      f32x4 st[4];
      __builtin_amdgcn_s_setprio(1);
#pragma unroll
      for (int f = 0; f < 4; f++) {
        bf16x8 bk0 = *(const bf16x8*)swz(Kc, f * 16 + l15, kq);
        bf16x8 bk1 = *(const bf16x8*)swz(Kc, f * 16 + l15, 32 + kq);
        f32x4 t = {};
        t = mfma16(bk0, aq0, t);
        t = mfma16(bk1, aq1, t);
        st[f] = t;
      }
      __builtin_amdgcn_s_setprio(0);
      if (kt == qb) {   // causal: kv_global > q_global -> -inf
#pragma unroll
        for (int f = 0; f < 4; f++) {
          int kvb = kt * 64 + f * 16 + rq;
#pragma unroll
          for (int r = 0; r < 4; r++)
            if (kvb + r > myq) st[f][r] = -1e30f;
        }
      }
      // per-thread row max over 16 kv + 2 shfl across rq-groups
      float mx = -1e30f;
#pragma unroll
      for (int f = 0; f < 4; f++)
#pragma unroll
        for (int r = 0; r < 4; r++) mx = fmaxf(mx, st[f][r]);
      mx = fmaxf(mx, __shfl_xor(mx, 16));
      mx = fmaxf(mx, __shfl_xor(mx, 32));
      const float mn = fmaxf(m_s, mx);
      const float alpha = exp2f(m_s - mn);
      m_s = mn;
#pragma unroll
      for (int f = 0; f < 4; f++)
#pragma unroll
        for (int r = 0; r < 4; r++) st[f][r] = exp2f(st[f][r] - mn);
      // alpha for PV row layout (q = w*16 + rq + r): source lane l15 = rq + r
      float alpr[4];
#pragma unroll
      for (int r = 0; r < 4; r++) alpr[r] = __shfl(alpha, rq + r);
#pragma unroll
      for (int ni = 0; ni < 4; ni++)
#pragma unroll
        for (int r = 0; r < 4; r++) oacc[ni][r] *= alpr[r];
#pragma unroll
      for (int r = 0; r < 4; r++) lacc[r] *= alpr[r];
      // P -> LDS: thread holds 4 consecutive kv at fixed q -> 4 b64 writes
#pragma unroll
      for (int f = 0; f < 4; f++) {
        us4 pk;
#pragma unroll
        for (int r = 0; r < 4; r++) pk.v[r] = f2bf(st[f][r]);
        *(us4*)swz(&Ps[0][0], w * 16 + l15, f * 16 + rq) = pk;
      }
      __builtin_amdgcn_s_setprio(1);
#pragma unroll
      for (int kk2 = 0; kk2 < 2; kk2++) {
        bf16x8 ap = *(const bf16x8*)swz(&Ps[0][0], w * 16 + l15, kk2 * 32 + kq);
        lacc = mfma16(ap, ones, lacc);
#pragma unroll
        for (int ni = 0; ni < 4; ni++) {
          bf16x8 bv = *(const bf16x8*)swz(Vc, ni * 16 + l15, kk2 * 32 + kq);
          oacc[ni] = mfma16(ap, bv, oacc[ni]);
        }
      }
      __builtin_amdgcn_s_setprio(0);
      __builtin_amdgcn_sched_barrier(0);  // keep reads+MFMA before next barrier
      bi++; if (bi >= 3) bi -= 3;
    }
    bf16_t* ob = o + ((size_t)(b * S_LEN + qb * 64 + w * 16 + rq)) * DIM + h * HDIM + l15;
#pragma unroll
    for (int r = 0; r < 4; r++) {
      float inv = 1.0f / lacc[r];
#pragma unroll
      for (int ni = 0; ni < 4; ni++)
        ob[(size_t)r * DIM + ni * 16] = __float2bfloat16(oacc[ni][r] * inv);
    }
  }
#undef STAGE
}

// ---------------------------------------------------------------------------
extern "C" void kernel_launch(void* const* d_in, const int* in_sizes, int n_in,
                              void* d_out, int out_size, void* d_ws, size_t ws_size,
                              hipStream_t stream) {
  (void)in_sizes; (void)n_in; (void)out_size; (void)ws_size;
  const float* x_processed = (const float*)d_in[0];
  const int*   boundaries  = (const int*)d_in[1];
  const int*   counts      = (const int*)d_in[2];
  const float* x_residual  = (const float*)d_in[3];
  const float* cos_t       = (const float*)d_in[4];
  const float* sin_t       = (const float*)d_in[5];
  // d_in[6] = seq_len (constant 2048, compiled in)
  const float* start_emb   = (const float*)d_in[7];
  const float* Wq  = (const float*)d_in[8];
  const float* Wk  = (const float*)d_in[9];
  const float* Wv  = (const float*)d_in[10];
  const float* Wo  = (const float*)d_in[11];
  const float* Wg  = (const float*)d_in[12];
  const float* Wu  = (const float*)d_in[13];
  const float* Wd  = (const float*)d_in[14];
  const float* ln1 = (const float*)d_in[15];
  const float* ln2 = (const float*)d_in[16];
  const float* fnm = (const float*)d_in[17];

  // Workspace layout (120 MB, lifetime-overlapped):
  char* ws = (char*)d_ws;
  const size_t MB = (size_t)1 << 20;
  float*  x      = (float*)(ws);            // 16MB  residual stream f32
  bf16_t* h      = (bf16_t*)(ws + 16 * MB); // 8MB   rms output bf16
  bf16_t* Wqkv_t = (bf16_t*)(ws + 24 * MB); // 6MB   [3072][1024]
  bf16_t* Wo_t   = (bf16_t*)(ws + 30 * MB); // 2MB   [1024][1024]
  bf16_t* Wgu_t  = (bf16_t*)(ws + 32 * MB); // 16MB  B̃[8192][1024] interleaved
  bf16_t* Wd_t   = (bf16_t*)(ws + 48 * MB); // 8MB   [1024][4096]
  char*   Rg     = ws + 56 * MB;            // 64MB shared region
  bf16_t* qkv  = (bf16_t*)(Rg);             // 24MB [4096][3072]
  bf16_t* vT   = (bf16_t*)(Rg + 24 * MB);   // 8MB  [32][64][2048]
  bf16_t* obuf = (bf16_t*)(Rg + 32 * MB);   // 8MB  [4096][1024]
  bf16_t* act  = (bf16_t*)(Rg);             // 32MB [4096][4096] (after attn)

  const size_t dd = (size_t)DIM * DIM, df = (size_t)DIM * FDIM;
  for (int l = 0; l < NLAYER; l++) {
    // layer 0: transposes + ragged expand fused in one launch
    const int nexp = (l == 0) ? NROW : 0;
    transpose_all<<<16384 + nexp, 256, 0, stream>>>(
        Wq + l * dd, Wk + l * dd, Wv + l * dd, Wo + l * dd,
        Wg + l * df, Wu + l * df, Wd + l * df,
        Wqkv_t, Wo_t, Wgu_t, Wd_t,
        x_processed, boundaries, counts, x_residual, start_emb, x);

    rmsnorm_kernel<0><<<NROW, 256, 0, stream>>>(x, ln1 + l * DIM, h, nullptr);
    gemm_bt256<2><<<(3072 / 256) * (NROW / 256), 512, 0, stream>>>(
        h, Wqkv_t, qkv, 3072, DIM, DIM, 3072 / 256, NROW / 256, cos_t, sin_t, vT);
    attn_kernel<<<512, 256, 0, stream>>>(qkv, vT, obuf);
    gemm_sn<1><<<(DIM / 64) * (NROW / 128), 256, 0, stream>>>(
        obuf, Wo_t, nullptr, x, DIM, DIM, DIM);

    rmsnorm_kernel<0><<<NROW, 256, 0, stream>>>(x, ln2 + l * DIM, h, nullptr);
    gemm_bt256<1><<<(2 * FDIM / 256) * (NROW / 256), 512, 0, stream>>>(
        h, Wgu_t, act, FDIM, DIM, DIM, 2 * FDIM / 256, NROW / 256,
        nullptr, nullptr, nullptr);
    gemm_sn<1><<<(DIM / 64) * (NROW / 128), 256, 0, stream>>>(
        act, Wd_t, nullptr, x, DIM, FDIM, FDIM);
  }
  rmsnorm_kernel<1><<<NROW, 256, 0, stream>>>(x, fnm, nullptr, (float*)d_out);
}

// Round 23
// 563.150 us; speedup vs baseline: 1.1094x; 1.0039x over previous
//
#include <hip/hip_runtime.h>
#include <hip/hip_bf16.h>

// Problem constants (fixed-shape problem)
#define S_LEN  2048
#define NB     2
#define DIM    1024
#define KSEG   256
#define NLAYER 2
#define NHEAD  16
#define HDIM   64
#define FDIM   4096
#define NROW   (NB * S_LEN)   // 4096 token rows

typedef __bf16 bf16x8 __attribute__((ext_vector_type(8)));
typedef float  f32x4  __attribute__((ext_vector_type(4)));
typedef __hip_bfloat16 bf16_t;

struct __align__(8)  us4 { unsigned short v[4]; };
struct __align__(16) us8 { unsigned short v[8]; };

__device__ __forceinline__ unsigned short f2bf(float f) {
  __hip_bfloat16 t = __float2bfloat16(f);
  return __builtin_bit_cast(unsigned short, t);
}
__device__ __forceinline__ float bf2f(unsigned short x) {
  return __bfloat162float(__builtin_bit_cast(__hip_bfloat16, x));
}

// Async global->LDS, 16B per lane. LDS dest must be wave-uniform base; HW
// scatters lane i at base + i*16 (guide §5 / m104).
__device__ __forceinline__ void gload_lds16(const void* g, void* l) {
  __builtin_amdgcn_global_load_lds((__attribute__((address_space(1))) void*)g,
                                   (__attribute__((address_space(3))) void*)l,
                                   16, 0, 0);
}

__device__ __forceinline__ f32x4 mfma16(bf16x8 a, bf16x8 b, f32x4 c) {
  return __builtin_amdgcn_mfma_f32_16x16x32_bf16(a, b, c, 0, 0, 0);
}

// XOR-swizzle accessor for [rows][64] bf16 LDS tiles (128B row stride, T2/G4):
// byte = (r*128 + kElem*2) ^ ((r&7)<<4). Spreads the 16-rows-same-column
// fragment read across 8 distinct 16B slots (residual 2-way = free).
__device__ __forceinline__ bf16_t* swz(bf16_t* base, int r, int kElem) {
  int byte = ((r << 7) + (kElem << 1)) ^ ((r & 7) << 4);
  return (bf16_t*)((char*)base + byte);
}
__device__ __forceinline__ const bf16_t* swz(const bf16_t* base, int r, int kElem) {
  int byte = ((r << 7) + (kElem << 1)) ^ ((r & 7) << 4);
  return (const bf16_t*)((const char*)base + byte);
}

// ---------------------------------------------------------------------------
// RMSNorm: out = x * rsqrt(mean(x^2)+eps) * w ; one block per row of 1024
// ---------------------------------------------------------------------------
template <int F32OUT>
__global__ __launch_bounds__(256) void rmsnorm_kernel(
    const float* __restrict__ x, const float* __restrict__ wgt,
    bf16_t* __restrict__ ob, float* __restrict__ of) {
  const int row = blockIdx.x, tid = threadIdx.x;
  const float4 v = ((const float4*)(x + (size_t)row * DIM))[tid];
  float ss = v.x * v.x + v.y * v.y + v.z * v.z + v.w * v.w;
#pragma unroll
  for (int off = 1; off < 64; off <<= 1) ss += __shfl_xor(ss, off);
  __shared__ float red[4];
  if ((tid & 63) == 0) red[tid >> 6] = ss;
  __syncthreads();
  ss = red[0] + red[1] + red[2] + red[3];
  const float r = rsqrtf(ss * (1.0f / DIM) + 1e-5f);
  const float4 wv = ((const float4*)wgt)[tid];
  if (F32OUT) {
    float4 o4; o4.x = v.x * r * wv.x; o4.y = v.y * r * wv.y;
    o4.z = v.z * r * wv.z; o4.w = v.w * r * wv.w;
    ((float4*)(of + (size_t)row * DIM))[tid] = o4;
  } else {
    us4 p;
    p.v[0] = f2bf(v.x * r * wv.x); p.v[1] = f2bf(v.y * r * wv.y);
    p.v[2] = f2bf(v.z * r * wv.z); p.v[3] = f2bf(v.w * r * wv.w);
    ((us4*)(ob + (size_t)row * DIM))[tid] = p;
  }
}

// ---------------------------------------------------------------------------
// Fused weight transpose+cast for ONE layer (all 7 weights) + optionally the
// ragged expand (folds the expand_kernel launch into layer-0's dispatch).
// Tile body identical to the proven transpose_cast (32x33-padded LDS tile).
// Block decode (wave-uniform):
//   [    0, 4096): Wq/Wk/Wv/Wo  1024x1024, 1024 tiles each, mode 0
//   [ 4096,12288): Wg/Wu        1024x4096, 4096 tiles each, gu-interleave
//                  (out row n -> (n>>4)*32 + (n&15) + 16*is_u)
//   [12288,16384): Wd           4096x1024, 4096 tiles, mode 0
//   [16384,16384+nexp): ragged expand + residual add (row = idx-16384)
// ---------------------------------------------------------------------------
__global__ __launch_bounds__(256) void transpose_all(
    const float* __restrict__ Wq, const float* __restrict__ Wk,
    const float* __restrict__ Wv, const float* __restrict__ Wo,
    const float* __restrict__ Wg, const float* __restrict__ Wu,
    const float* __restrict__ Wd,
    bf16_t* __restrict__ Wqkv_t, bf16_t* __restrict__ Wo_t,
    bf16_t* __restrict__ Wgu_t, bf16_t* __restrict__ Wd_t,
    const float* __restrict__ xp, const int* __restrict__ bnd,
    const int* __restrict__ counts, const float* __restrict__ xres,
    const float* __restrict__ semb, float* __restrict__ x) {
  __shared__ float tile[32][33];
  const int tx = threadIdx.x & 31, ty = threadIdx.x >> 5;  // 32 x 8
  const int idx = blockIdx.x;
  if (idx >= 16384) {        // ragged expand + residual add (layer 0 only)
    const int bt = idx - 16384;
    const int b = bt >> 11, t = bt & (S_LEN - 1);
    const int cnt = counts[b];
    const int* bb = bnd + b * KSEG;
    int lo = 0, hi = KSEG;
    while (lo < hi) {
      int mid = (lo + hi) >> 1;
      int v = (mid < cnt) ? bb[mid] : S_LEN;
      if (v < t) lo = mid + 1; else hi = mid;
    }
    const float* src = (lo == 0) ? semb
                                 : (xp + ((size_t)b * KSEG + (lo - 1)) * DIM);
    const int tid = threadIdx.x;
    float4 a = ((const float4*)src)[tid];
    float4 r = ((const float4*)(xres + (size_t)bt * DIM))[tid];
    float4 w; w.x = a.x + r.x; w.y = a.y + r.y; w.z = a.z + r.z; w.w = a.w + r.w;
    ((float4*)(x + (size_t)bt * DIM))[tid] = w;
    return;
  }
  const float* in;
  bf16_t* out;
  int R, C, bx, by, mode = 0;
  if (idx < 4096) {          // Wq / Wk / Wv / Wo
    const int which = idx >> 10, t = idx & 1023;
    R = 1024; C = 1024;
    bx = t & 31; by = t >> 5;
    if (which == 0)      { in = Wq; out = Wqkv_t; }
    else if (which == 1) { in = Wk; out = Wqkv_t + 1024 * 1024; }
    else if (which == 2) { in = Wv; out = Wqkv_t + 2 * 1024 * 1024; }
    else                 { in = Wo; out = Wo_t; }
  } else if (idx < 12288) {  // Wg (mode 1) / Wu (mode 2) -> interleaved B̃
    const int j = idx - 4096;
    const int which = j >> 12, t = j & 4095;
    R = 1024; C = 4096;
    bx = t & 127; by = t >> 7;
    in = which ? Wu : Wg; out = Wgu_t; mode = which ? 2 : 1;
  } else {                   // Wd
    const int t = idx - 12288;
    R = 4096; C = 1024;
    bx = t & 31; by = t >> 5;
    in = Wd; out = Wd_t;
  }
  const int cb = bx * 32, rb = by * 32;
#pragma unroll
  for (int i = 0; i < 4; i++) {
    int r = ty + i * 8;
    tile[r][tx] = in[(size_t)(rb + r) * C + cb + tx];
  }
  __syncthreads();
#pragma unroll
  for (int i = 0; i < 4; i++) {
    int r = ty + i * 8;
    int n = cb + r;
    int dr = (mode == 0) ? n : (((n >> 4) << 5) + (n & 15) + (mode == 2 ? 16 : 0));
    out[(size_t)dr * R + rb + tx] = __float2bfloat16(tile[tx][r]);
  }
}

// ---------------------------------------------------------------------------
// 256x256 / BK=64 / 8-wave (2Mx4N) 8-phase GEMM, C = A[M,K] @ Bt[N,K]^T.
// m201 template: double-buffered 128KB LDS, T2 XOR-swizzle, counted vmcnt(6)
// at tile boundaries only, two raw barriers per phase, setprio around the
// MFMA cluster, rectangular per-XCD block swizzle.
// FUSE 0: C[r][c] = bf16(acc), ldc = N.
// FUSE 1: B̃ gu-interleaved; writes silu(g)*u (ldc 4096).
// FUSE 2: QKV with fused RoPE on q/k sections (bn<8); v sections (bn>=8)
//         write vT[(bh*64+dh)*2048 + t] DIRECTLY and skip the C store.
// ---------------------------------------------------------------------------
template <int FUSE>
__global__ __launch_bounds__(512, 2) void gemm_bt256(
    const bf16_t* __restrict__ A, const bf16_t* __restrict__ Bt,
    bf16_t* __restrict__ C, int ldc, int K, int lda, int nbn, int nbm,
    const float* __restrict__ cosb, const float* __restrict__ sinb,
    bf16_t* __restrict__ vTout) {
  __shared__ __align__(16) bf16_t As[2][256][64];
  __shared__ __align__(16) bf16_t Bs[2][256][64];
  const int bid = blockIdx.x;
  const int bmC = nbm >> 1, bnC = nbn >> 2;
  const int c8 = bid & 7, idx = bid >> 3;
  const int bm = (c8 & 1) * bmC + idx / bnC;
  const int bn = (c8 >> 1) * bnC + idx % bnC;
  const int tid = threadIdx.x;
  const int lane = tid & 63, w = tid >> 6;
  const int wm = w >> 2, wn = w & 3;               // 2M x 4N wave grid
  const int l15 = lane & 15, l16 = lane >> 4;
  const bf16_t* Ag = A + (size_t)bm * 256 * lda;
  const bf16_t* Bg = Bt + (size_t)bn * 256 * K;
  const int NT = K >> 6;

  f32x4 acc[8][4] = {};

  auto stage = [&](int j) {
    const int t = j >> 2, item = j & 3, buf = t & 1;
    bf16_t* dst;
    const bf16_t* src;
    int stride;
    if (item < 2) { dst = &Bs[buf][item * 128][0];
                    src = Bg + (size_t)item * 128 * K;  stride = K;   }
    else          { dst = &As[buf][(item - 2) * 128][0];
                    src = Ag + (size_t)(item - 2) * 128 * lda; stride = lda; }
    const int k0 = t << 6;
#pragma unroll
    for (int i = 0; i < 2; i++) {
      int c = i * 512 + tid;
      int row = c >> 3, q = c & 7;
      int colE = (q ^ (row & 7)) << 3;   // inverse swizzle on global source
      gload_lds16(src + (size_t)row * stride + k0 + colE, dst + c * 8);
    }
  };
  auto frag = [&](const bf16_t* tile, int row, int kk) -> bf16x8 {
    int byte = ((row << 7) + (kk << 6) + (l16 << 4)) ^ ((row & 7) << 4);
    return *(const bf16x8*)((const char*)tile + byte);
  };

  for (int j = 0; j < 7; j++) stage(j);
  asm volatile("s_waitcnt vmcnt(6)" ::: "memory");
  __builtin_amdgcn_s_barrier();

  for (int t = 0; t < NT; t++) {
    const int buf = t & 1;
    const bf16_t* At = &As[buf][0][0];
    const bf16_t* Bc = &Bs[buf][0][0];
    bf16x8 bfrg[4][2];
    const int jb = (t << 2) + 7;
#pragma unroll
    for (int p = 0; p < 4; p++) {
      bf16x8 afrg[2][2];
      if (p == 0) {
#pragma unroll
        for (int ni = 0; ni < 4; ni++)
#pragma unroll
          for (int kk = 0; kk < 2; kk++)
            bfrg[ni][kk] = frag(Bc, wn * 64 + ni * 16 + l15, kk);
      }
#pragma unroll
      for (int mi = 0; mi < 2; mi++)
#pragma unroll
        for (int kk = 0; kk < 2; kk++)
          afrg[mi][kk] = frag(At, wm * 128 + p * 32 + mi * 16 + l15, kk);
      if (jb + p < 4 * NT) stage(jb + p);
      __builtin_amdgcn_sched_barrier(0);
      __builtin_amdgcn_s_barrier();
      asm volatile("s_waitcnt lgkmcnt(0)" ::: "memory");
      __builtin_amdgcn_sched_barrier(0);
      __builtin_amdgcn_s_setprio(1);
#pragma unroll
      for (int mi = 0; mi < 2; mi++)
#pragma unroll
        for (int ni = 0; ni < 4; ni++)
#pragma unroll
          for (int kk = 0; kk < 2; kk++)
            acc[p * 2 + mi][ni] = mfma16(afrg[mi][kk], bfrg[ni][kk],
                                         acc[p * 2 + mi][ni]);
      __builtin_amdgcn_s_setprio(0);
      __builtin_amdgcn_sched_barrier(0);
      if (p == 3) {
        if (t < NT - 2) { asm volatile("s_waitcnt vmcnt(6)" ::: "memory"); }
        else            { asm volatile("s_waitcnt vmcnt(0)" ::: "memory"); }
      }
      __builtin_amdgcn_s_barrier();
    }
  }

  const int r0 = bm * 256 + wm * 128 + (l16 << 2);
  if (FUSE == 0) {
    const int c0 = bn * 256 + wn * 64 + l15;
#pragma unroll
    for (int mi = 0; mi < 8; mi++)
#pragma unroll
      for (int ni = 0; ni < 4; ni++)
#pragma unroll
        for (int r = 0; r < 4; r++)
          C[(size_t)(r0 + mi * 16 + r) * ldc + c0 + ni * 16] =
              __float2bfloat16(acc[mi][ni][r]);
  } else if (FUSE == 1) {
    const int c0 = bn * 128 + wn * 32 + l15;
#pragma unroll
    for (int mi = 0; mi < 8; mi++)
#pragma unroll
      for (int j = 0; j < 2; j++)
#pragma unroll
        for (int r = 0; r < 4; r++) {
          float g = acc[mi][2 * j][r], u = acc[mi][2 * j + 1][r];
          float a = g / (1.f + __expf(-g)) * u;
          C[(size_t)(r0 + mi * 16 + r) * ldc + c0 + j * 16] = __float2bfloat16(a);
        }
  } else {  // FUSE == 2
    const int c0 = bn * 256 + wn * 64 + l15;
    if (bn < 8) {   // q/k: cols < 2048 -> RoPE then store to qkv
#pragma unroll
      for (int mi = 0; mi < 8; mi++)
#pragma unroll
        for (int r = 0; r < 4; r++) {
          const int row = r0 + mi * 16 + r;
          const int tt = row & (S_LEN - 1);
#pragma unroll
          for (int ni = 0; ni < 2; ni++) {
            const int i = ni * 16 + l15;
            const float cz = cosb[tt * HDIM + i];
            const float sz = sinb[tt * HDIM + i];
            const float x1 = acc[mi][ni][r], x2 = acc[mi][ni + 2][r];
            C[(size_t)row * ldc + c0 + ni * 16] =
                __float2bfloat16(x1 * cz - x2 * sz);
            C[(size_t)row * ldc + c0 + (ni + 2) * 16] =
                __float2bfloat16(x2 * cz + x1 * sz);
          }
        }
    } else {        // v section: write vT[(bh*64+dh)*2048 + t] directly
      const int hh = (bn - 8) * 4 + wn;
      const int b = r0 >> 11, t0 = r0 & (S_LEN - 1);
#pragma unroll
      for (int mi = 0; mi < 8; mi++)
#pragma unroll
        for (int ni = 0; ni < 4; ni++) {
          us4 pk;
#pragma unroll
          for (int r = 0; r < 4; r++) pk.v[r] = f2bf(acc[mi][ni][r]);
          *(us4*)&vTout[((size_t)((b << 4) + hh) * 64 + ni * 16 + l15) * S_LEN
                        + t0 + mi * 16] = pk;
        }
    }
  }
}

// ---------------------------------------------------------------------------
// Small-N GEMM: 128M x 64N tile, BK=64, 256 threads / 4 waves (2M x 2N),
// ring-3 LDS (72KB -> 2 independent blocks/CU), depth-2 counted vmcnt
// (6 loads/thread/stage -> vmcnt(6)/vmcnt(0)). One raw s_barrier per iter.
// EPI 0: C bf16 store; EPI 1: Cf (f32) += acc  (fused residual add)
// ---------------------------------------------------------------------------
template <int EPI>
__global__ __launch_bounds__(256) void gemm_sn(
    const bf16_t* __restrict__ A, const bf16_t* __restrict__ Bt,
    bf16_t* __restrict__ Cb, float* __restrict__ Cf, int N, int K, int lda) {
  __shared__ __align__(16) bf16_t As[3][128][64];   // 16KB each
  __shared__ __align__(16) bf16_t Bs[3][64][64];    // 8KB each
  const int nbn = N >> 6;
  const int bid = blockIdx.x;
  const int sbid = (bid & 7) * (gridDim.x >> 3) + (bid >> 3);  // XCD-chunked
  const int bn = sbid % nbn, bm = sbid / nbn;
  const int tid = threadIdx.x, lane = tid & 63, w = tid >> 6;
  const int wm = w >> 1, wn = w & 1;              // 2M x 2N wave grid
  const int l15 = lane & 15, l16 = lane >> 4;
  const bf16_t* Ag = A + (size_t)bm * 128 * lda;
  const bf16_t* Bg = Bt + (size_t)bn * 64 * K;
  f32x4 acc[4][2] = {};
  const int NT = K >> 6;

  // stage: A 16KB (1024 chunks, 4/thread) + B 8KB (512 chunks, 2/thread)
  auto stage = [&](int buf, int t) {
    const int k0 = t << 6;
#pragma unroll
    for (int i = 0; i < 4; i++) {
      int c = i * 256 + tid;
      int row = c >> 3, q = c & 7;
      int colE = (q ^ (row & 7)) << 3;            // inverse swizzle on source
      gload_lds16(Ag + (size_t)row * lda + k0 + colE, &As[buf][0][0] + c * 8);
    }
#pragma unroll
    for (int i = 0; i < 2; i++) {
      int c = i * 256 + tid;
      int row = c >> 3, q = c & 7;
      int colE = (q ^ (row & 7)) << 3;
      gload_lds16(Bg + (size_t)row * K + k0 + colE, &Bs[buf][0][0] + c * 8);
    }
  };
  // swizzled fragment read: kk = K-half (0/1), 16B slot = kk*4 + l16
  auto frag = [&](const bf16_t* base, int row, int kk) -> bf16x8 {
    int byte = ((row << 7) + (kk << 6) + (l16 << 4)) ^ ((row & 7) << 4);
    return *(const bf16x8*)((const char*)base + byte);
  };

  stage(0, 0);
  if (NT > 1) stage(1, 1);
  int bi = 0;
  for (int t = 0; t < NT; t++) {
    if (t + 1 < NT) { asm volatile("s_waitcnt vmcnt(6)" ::: "memory"); }
    else            { asm volatile("s_waitcnt vmcnt(0)" ::: "memory"); }
    __builtin_amdgcn_s_barrier();
    __builtin_amdgcn_sched_barrier(0);
    if (t + 2 < NT) {
      int nb = bi + 2; if (nb >= 3) nb -= 3;
      stage(nb, t + 2);
    }
    __builtin_amdgcn_sched_barrier(0);
    const bf16_t* Ab = &As[bi][0][0];
    const bf16_t* Bb = &Bs[bi][0][0];
    bf16x8 af[4][2], bfr[2][2];
#pragma unroll
    for (int mi = 0; mi < 4; mi++)
#pragma unroll
      for (int kk = 0; kk < 2; kk++)
        af[mi][kk] = frag(Ab, wm * 64 + mi * 16 + l15, kk);
#pragma unroll
    for (int ni = 0; ni < 2; ni++)
#pragma unroll
      for (int kk = 0; kk < 2; kk++)
        bfr[ni][kk] = frag(Bb, wn * 32 + ni * 16 + l15, kk);
    __builtin_amdgcn_s_setprio(1);
#pragma unroll
    for (int mi = 0; mi < 4; mi++)
#pragma unroll
      for (int ni = 0; ni < 2; ni++)
#pragma unroll
        for (int kk = 0; kk < 2; kk++)
          acc[mi][ni] = mfma16(af[mi][kk], bfr[ni][kk], acc[mi][ni]);
    __builtin_amdgcn_s_setprio(0);
    __builtin_amdgcn_sched_barrier(0);   // keep reads+MFMA before next barrier
    bi++; if (bi >= 3) bi -= 3;
  }

  const int r0 = bm * 128 + wm * 64 + (l16 << 2);
  const int c0 = bn * 64 + wn * 32 + l15;
#pragma unroll
  for (int mi = 0; mi < 4; mi++)
#pragma unroll
    for (int ni = 0; ni < 2; ni++)
#pragma unroll
      for (int r = 0; r < 4; r++) {
        size_t off = (size_t)(r0 + mi * 16 + r) * N + c0 + ni * 16;
        if (EPI == 0) Cb[off] = __float2bfloat16(acc[mi][ni][r]);
        else          Cf[off] += acc[mi][ni][r];
      }
}

// ---------------------------------------------------------------------------
// Flash attention (r15/r17 structure, measured best): block = (bh, pair)
// covering 64-row q-tiles {p, 31-p} (exact balance, grid 512 = 2 blocks/CU
// for decoupled TLP). Ring-3 K/V buffers, depth-2 counted vmcnt, one raw
// barrier per step. S^T-swapped QK (per-thread one q = l15, 16 kv):
// in-thread max + 2 shfl softmax; P packed 4xbf16 -> b64 writes; alpha
// redistributed via 4 shfls; row-sum via MFMA ones-column; exp2 softmax.
// ---------------------------------------------------------------------------
__global__ __launch_bounds__(256) void attn_kernel(
    const bf16_t* __restrict__ qkv, const bf16_t* __restrict__ vT,
    bf16_t* __restrict__ o) {
  __shared__ __align__(16) bf16_t Ks[3][64][64];
  __shared__ __align__(16) bf16_t Vs[3][64][64];
  __shared__ __align__(16) bf16_t Ps[64][64];
  const int bid = blockIdx.x;
  const int pair = (bid >> 3) & 15;
  const int bh = (bid & 7) + ((bid >> 7) << 3);
  const int b = bh >> 4, h = bh & 15;
  const int tid = threadIdx.x, lane = tid & 63, w = tid >> 6;
  const int l15 = lane & 15;
  const int kq = (lane >> 4) << 3;
  const int rq = (lane >> 4) << 2;
  const bf16_t* kbase = qkv + (size_t)b * S_LEN * 3072 + 1024 + h * HDIM;
  const bf16_t* vbase = vT + ((size_t)bh * 64) * S_LEN;

  bf16x8 ones;
#pragma unroll
  for (int e = 0; e < 8; e++) ones[e] = (__bf16)1.0f;

#define STAGE(buf, kt) do {                                                    \
    const bf16_t* kg_ = kbase + (size_t)(kt) * 64 * 3072;                      \
    const bf16_t* vg_ = vbase + (kt) * 64;                                     \
    _Pragma("unroll")                                                          \
    for (int i_ = 0; i_ < 2; i_++) {                                           \
      int cb_ = i_ * 256 + w * 64;                                             \
      int c_ = cb_ + lane;                                                     \
      int row_ = c_ >> 3;                                                      \
      int colE_ = ((c_ & 7) ^ (row_ & 7)) << 3;                                \
      gload_lds16(kg_ + (size_t)row_ * 3072 + colE_,                           \
                  &Ks[buf][0][0] + (size_t)cb_ * 8);                           \
      gload_lds16(vg_ + (size_t)row_ * S_LEN + colE_,                          \
                  &Vs[buf][0][0] + (size_t)cb_ * 8);                           \
    }                                                                          \
  } while (0)

  for (int ph = 0; ph < 2; ph++) {
    const int qb = (ph == 0) ? pair : (31 - pair);
    const int nk = qb + 1;
    const int qrow = qb * 64 + w * 16 + l15;
    const bf16_t* qg = qkv + ((size_t)(b * S_LEN + qrow)) * 3072 + h * HDIM;
    bf16x8 aq0 = *(const bf16x8*)(qg + kq);
    bf16x8 aq1 = *(const bf16x8*)(qg + 32 + kq);
    const float qsc = 0.125f * 1.44269504088896340736f;
#pragma unroll
    for (int e = 0; e < 8; e++) {
      aq0[e] = (__bf16)((float)aq0[e] * qsc);
      aq1[e] = (__bf16)((float)aq1[e] * qsc);
    }
    f32x4 oacc[4] = {};
    f32x4 lacc = {0.f, 0.f, 0.f, 0.f};
    float m_s = -1e30f;                 // per-thread q = w*16 + l15
    const int myq = qb * 64 + w * 16 + l15;

    // protect ring buffers from the previous phase's readers (cross-wave)
    __builtin_amdgcn_s_barrier();
    STAGE(0, 0);
    if (nk > 1) STAGE(1, 1);
    int bi = 0;
    for (int kt = 0; kt < nk; kt++) {
      if (kt + 1 < nk) { asm volatile("s_waitcnt vmcnt(4)" ::: "memory"); }
      else             { asm volatile("s_waitcnt vmcnt(0)" ::: "memory"); }
      __builtin_amdgcn_s_barrier();
      __builtin_amdgcn_sched_barrier(0);
      if (kt + 2 < nk) {
        int nb = bi + 2; if (nb >= 3) nb -= 3;
        STAGE(nb, kt + 2);
      }
      __builtin_amdgcn_sched_barrier(0);
      const bf16_t* Kc = &Ks[bi][0][0];
      const bf16_t* Vc = &Vs[bi][0][0];
      // S^T = K Q^T (swapped operands): col = q (l15), row = kv (rq + reg)
      f32x4 st[4];
      __builtin_amdgcn_s_setprio(1);
#pragma unroll
      for (int f = 0; f < 4; f++) {
        bf16x8 bk0 = *(const bf16x8*)swz(Kc, f * 16 + l15, kq);
        bf16x8 bk1 = *(const bf16x8*)swz(Kc, f * 16 + l15, 32 + kq);
        f32x4 t = {};
        t = mfma16(bk0, aq0, t);
        t = mfma16(bk1, aq1, t);
        st[f] = t;
      }
      __builtin_amdgcn_s_setprio(0);
      if (kt == qb) {   // causal: kv_global > q_global -> -inf
#pragma unroll
        for (int f = 0; f < 4; f++) {
          int kvb = kt * 64 + f * 16 + rq;
#pragma unroll
          for (int r = 0; r < 4; r++)
            if (kvb + r > myq) st[f][r] = -1e30f;
        }
      }
      // per-thread row max over 16 kv + 2 shfl across rq-groups
      float mx = -1e30f;
#pragma unroll
      for (int f = 0; f < 4; f++)
#pragma unroll
        for (int r = 0; r < 4; r++) mx = fmaxf(mx, st[f][r]);
      mx = fmaxf(mx, __shfl_xor(mx, 16));
      mx = fmaxf(mx, __shfl_xor(mx, 32));
      const float mn = fmaxf(m_s, mx);
      const float alpha = exp2f(m_s - mn);
      m_s = mn;
#pragma unroll
      for (int f = 0; f < 4; f++)
#pragma unroll
        for (int r = 0; r < 4; r++) st[f][r] = exp2f(st[f][r] - mn);
      // alpha for PV row layout (q = w*16 + rq + r): source lane l15 = rq + r
      float alpr[4];
#pragma unroll
      for (int r = 0; r < 4; r++) alpr[r] = __shfl(alpha, rq + r);
#pragma unroll
      for (int ni = 0; ni < 4; ni++)
#pragma unroll
        for (int r = 0; r < 4; r++) oacc[ni][r] *= alpr[r];
#pragma unroll
      for (int r = 0; r < 4; r++) lacc[r] *= alpr[r];
      // P -> LDS: thread holds 4 consecutive kv at fixed q -> 4 b64 writes
#pragma unroll
      for (int f = 0; f < 4; f++) {
        us4 pk;
#pragma unroll
        for (int r = 0; r < 4; r++) pk.v[r] = f2bf(st[f][r]);
        *(us4*)swz(&Ps[0][0], w * 16 + l15, f * 16 + rq) = pk;
      }
      __builtin_amdgcn_s_setprio(1);
#pragma unroll
      for (int kk2 = 0; kk2 < 2; kk2++) {
        bf16x8 ap = *(const bf16x8*)swz(&Ps[0][0], w * 16 + l15, kk2 * 32 + kq);
        lacc = mfma16(ap, ones, lacc);
#pragma unroll
        for (int ni = 0; ni < 4; ni++) {
          bf16x8 bv = *(const bf16x8*)swz(Vc, ni * 16 + l15, kk2 * 32 + kq);
          oacc[ni] = mfma16(ap, bv, oacc[ni]);
        }
      }
      __builtin_amdgcn_s_setprio(0);
      __builtin_amdgcn_sched_barrier(0);  // keep reads+MFMA before next barrier
      bi++; if (bi >= 3) bi -= 3;
    }
    bf16_t* ob = o + ((size_t)(b * S_LEN + qb * 64 + w * 16 + rq)) * DIM + h * HDIM + l15;
#pragma unroll
    for (int r = 0; r < 4; r++) {
      float inv = 1.0f / lacc[r];
#pragma unroll
      for (int ni = 0; ni < 4; ni++)
        ob[(size_t)r * DIM + ni * 16] = __float2bfloat16(oacc[ni][r] * inv);
    }
  }
#undef STAGE
}

// ---------------------------------------------------------------------------
extern "C" void kernel_launch(void* const* d_in, const int* in_sizes, int n_in,
                              void* d_out, int out_size, void* d_ws, size_t ws_size,
                              hipStream_t stream) {
  (void)in_sizes; (void)n_in; (void)out_size; (void)ws_size;
  const float* x_processed = (const float*)d_in[0];
  const int*   boundaries  = (const int*)d_in[1];
  const int*   counts      = (const int*)d_in[2];
  const float* x_residual  = (const float*)d_in[3];
  const float* cos_t       = (const float*)d_in[4];
  const float* sin_t       = (const float*)d_in[5];
  // d_in[6] = seq_len (constant 2048, compiled in)
  const float* start_emb   = (const float*)d_in[7];
  const float* Wq  = (const float*)d_in[8];
  const float* Wk  = (const float*)d_in[9];
  const float* Wv  = (const float*)d_in[10];
  const float* Wo  = (const float*)d_in[11];
  const float* Wg  = (const float*)d_in[12];
  const float* Wu  = (const float*)d_in[13];
  const float* Wd  = (const float*)d_in[14];
  const float* ln1 = (const float*)d_in[15];
  const float* ln2 = (const float*)d_in[16];
  const float* fnm = (const float*)d_in[17];

  // Workspace layout (120 MB, lifetime-overlapped):
  char* ws = (char*)d_ws;
  const size_t MB = (size_t)1 << 20;
  float*  x      = (float*)(ws);            // 16MB  residual stream f32
  bf16_t* h      = (bf16_t*)(ws + 16 * MB); // 8MB   rms output bf16
  bf16_t* Wqkv_t = (bf16_t*)(ws + 24 * MB); // 6MB   [3072][1024]
  bf16_t* Wo_t   = (bf16_t*)(ws + 30 * MB); // 2MB   [1024][1024]
  bf16_t* Wgu_t  = (bf16_t*)(ws + 32 * MB); // 16MB  B̃[8192][1024] interleaved
  bf16_t* Wd_t   = (bf16_t*)(ws + 48 * MB); // 8MB   [1024][4096]
  char*   Rg     = ws + 56 * MB;            // 64MB shared region
  bf16_t* qkv  = (bf16_t*)(Rg);             // 24MB [4096][3072]
  bf16_t* vT   = (bf16_t*)(Rg + 24 * MB);   // 8MB  [32][64][2048]
  bf16_t* obuf = (bf16_t*)(Rg + 32 * MB);   // 8MB  [4096][1024]
  bf16_t* act  = (bf16_t*)(Rg);             // 32MB [4096][4096] (after attn)

  const size_t dd = (size_t)DIM * DIM, df = (size_t)DIM * FDIM;
  for (int l = 0; l < NLAYER; l++) {
    // layer 0: transposes + ragged expand fused in one launch
    const int nexp = (l == 0) ? NROW : 0;
    transpose_all<<<16384 + nexp, 256, 0, stream>>>(
        Wq + l * dd, Wk + l * dd, Wv + l * dd, Wo + l * dd,
        Wg + l * df, Wu + l * df, Wd + l * df,
        Wqkv_t, Wo_t, Wgu_t, Wd_t,
        x_processed, boundaries, counts, x_residual, start_emb, x);

    rmsnorm_kernel<0><<<NROW, 256, 0, stream>>>(x, ln1 + l * DIM, h, nullptr);
    gemm_bt256<2><<<(3072 / 256) * (NROW / 256), 512, 0, stream>>>(
        h, Wqkv_t, qkv, 3072, DIM, DIM, 3072 / 256, NROW / 256, cos_t, sin_t, vT);
    attn_kernel<<<512, 256, 0, stream>>>(qkv, vT, obuf);
    gemm_sn<1><<<(DIM / 64) * (NROW / 128), 256, 0, stream>>>(
        obuf, Wo_t, nullptr, x, DIM, DIM, DIM);

    rmsnorm_kernel<0><<<NROW, 256, 0, stream>>>(x, ln2 + l * DIM, h, nullptr);
    gemm_bt256<1><<<(2 * FDIM / 256) * (NROW / 256), 512, 0, stream>>>(
        h, Wgu_t, act, FDIM, DIM, DIM, 2 * FDIM / 256, NROW / 256,
        nullptr, nullptr, nullptr);
    gemm_sn<1><<<(DIM / 64) * (NROW / 128), 256, 0, stream>>>(
        act, Wd_t, nullptr, x, DIM, FDIM, FDIM);
  }
  rmsnorm_kernel<1><<<NROW, 256, 0, stream>>>(x, fnm, nullptr, (float*)d_out);
}